// Round 2
// baseline (445.601 us; speedup 1.0000x reference)
//
#include <hip/hip_runtime.h>

// 4-layer GRU stack, B=4096, T=256 — LAYER-PER-WAVE rewrite.
//
// 256 blocks x 256 threads (4 waves, 1/SIMD). Wave l owns layer l for all
// 16 batch rows and ALL units -> the recurrent h@rk matmul is wave-local
// (write h to LDS, read own A-frags back, no barrier). Cross-layer handoff
// uses superstep skew: in superstep sg, layer l computes t in
// [(sg-l)*8, (sg-l)*8+8), consuming layer l-1's outputs written in
// superstep sg-1 from 16-plane LDS rings. ONE barrier per 8 steps
// (36 total vs 520 before).
//
// Within a superstep the gate is deferred one step (gate(t) overlaps
// MFMA(t+1)), but the block-closing gate runs BEFORE the barrier so the
// consumer layer never races the last t of a block.
//
// True minimal MFMA counts (36/18/12/12 per step = 78/CU vs 128 before;
// no zero-padded weight MFMAs). Biases ride the first MFMA's C operand
// (no per-step acc-init movs). L0's 24 recurrent weight frags are
// streamed from LDS each step to keep VGPRs ~<400.
//
// Arithmetic is op-for-op identical to the previous kernel (same MFMA
// accumulation order, same gate math) -> absmax must stay 0.00390625.

typedef __attribute__((ext_vector_type(8))) __bf16 bf16x8;
typedef __attribute__((ext_vector_type(4))) float f32x4;

#define TT 256
#define FF 20
#define BT 16
#define KS 8            // steps per superstep
#define NSUP 35         // 32 active supersteps for L0 + 3 skew
#define XSTR 40         // x plane row stride (bf16), 16B-aligned, <=2-way banks
#define H0STR 72        // h0 row stride (64 units + pad)
#define H1STR 40        // h1/h2/h3 row stride (32 units + pad)
#define XPL (16 * XSTR)   // 640
#define H0PL (16 * H0STR) // 1152
#define H1PL (16 * H1STR) // 640
#define W0PL (16 * H0STR) // w0 pair-plane elems (16 cols x 72)
#define NTHR 256

__device__ __forceinline__ f32x4 mfma16(bf16x8 a, bf16x8 b, f32x4 c) {
  return __builtin_amdgcn_mfma_f32_16x16x32_bf16(a, b, c, 0, 0, 0);
}

__device__ __forceinline__ float sigm(float x) {
  return __builtin_amdgcn_rcpf(1.f + __builtin_amdgcn_exp2f(-1.44269504f * x));
}
__device__ __forceinline__ float tanh_(float x) {
  return __builtin_amdgcn_rcpf(1.f + __builtin_amdgcn_exp2f(-2.88539008f * x)) * 2.f - 1.f;
}

__device__ __forceinline__ bf16x8 bfragW(const float* W, int Kreal, int N,
                                         int ncol, int kbase) {
  bf16x8 r;
#pragma unroll
  for (int j = 0; j < 8; ++j) {
    int k = kbase + j;
    r[j] = (__bf16)(k < Kreal ? W[k * N + ncol] : 0.f);
  }
  return r;
}

extern "C" __global__ void __launch_bounds__(NTHR, 1)
gru4(const float* __restrict__ inp, const float* __restrict__ Wemb,
     const float* __restrict__ k0, const float* __restrict__ rk0, const float* __restrict__ b0,
     const float* __restrict__ k1, const float* __restrict__ rk1, const float* __restrict__ b1,
     const float* __restrict__ k2, const float* __restrict__ rk2, const float* __restrict__ b2,
     const float* __restrict__ k3, const float* __restrict__ rk3, const float* __restrict__ b3,
     const float* __restrict__ Wd, const float* __restrict__ bd,
     float* __restrict__ out)
{
  __shared__ __align__(16) __bf16 xring[16 * XPL];    // 20.5 KB (16 t-planes)
  __shared__ __align__(16) __bf16 h0ring[16 * H0PL];  // 36.9 KB
  __shared__ __align__(16) __bf16 h1ring[16 * H1PL];  // 20.5 KB
  __shared__ __align__(16) __bf16 h2ring[16 * H1PL];  // 20.5 KB
  __shared__ __align__(16) __bf16 h3s[2 * H1PL];      //  2.6 KB (L3 recurrent scratch)
  __shared__ __align__(16) __bf16 w0p[12 * W0PL];     // 27.6 KB (L0 streamed rk0 frags)
  __shared__ __align__(16) float h3f[BT * 32];

  const int tid  = threadIdx.x;
  const int lane = tid & 63;
  const int w    = tid >> 6;        // wave 0..3 = layer
  const int c    = lane & 15;       // A-frag row (batch) / B-frag col / C col
  const int kb   = (lane >> 4) * 8; // k base within a 32-k frag
  const int rq   = (lane >> 4) * 4; // C row base (batch)
  const long bbase = (long)blockIdx.x * BT;
  const float* binp = inp + bbase * TT * FF;

  bf16x8 zf;
#pragma unroll
  for (int j = 0; j < 8; ++j) zf[j] = (__bf16)0.f;

  // ---------------- prologue: zero rings, build w0p, stage t=0..7 ----------------
  for (int i = tid; i < 16 * H0PL; i += NTHR) h0ring[i] = (__bf16)0.f;
  for (int i = tid; i < 16 * H1PL; i += NTHR) { h1ring[i] = (__bf16)0.f; h2ring[i] = (__bf16)0.f; }
  for (int i = tid; i < 2 * H1PL; i += NTHR) h3s[i] = (__bf16)0.f;
  // w0p pair-planes: p = g*4+sl (g: 0=z,1=r,2=gh), [p][col][k0..63] = rk0[k][gbase + sl*16 + col]
  for (int e = tid; e < 12 * 16 * 64; e += NTHR) {
    int p = e >> 10, rem = e & 1023, cc = rem >> 6, kk = rem & 63;
    int g = p >> 2;
    int gb = (g == 0) ? 0 : (g == 1) ? 64 : 128;
    w0p[p * W0PL + cc * H0STR + kk] = (__bf16)rk0[kk * 192 + gb + (p & 3) * 16 + cc];
  }

  auto stageX = [&](int tstart) {
    // 128 row-jobs on threads 128..255 (waves 2,3 — the light ones)
    int j = tid - 128;
    if (j >= 0) {
      int tp = j >> 4, row = j & 15;
      int t = tstart + tp;
      const float* p = binp + ((long)row * TT + t) * FF;
      float4 v0 = *(const float4*)(p);
      float4 v1 = *(const float4*)(p + 4);
      float4 v2 = *(const float4*)(p + 8);
      float4 v3 = *(const float4*)(p + 12);
      float4 v4 = *(const float4*)(p + 16);
      float4 e  = *(const float4*)(Wemb + 4 * (int)v0.y);
      __bf16* d = &xring[(t & 15) * XPL + row * XSTR];
      bf16x8 q0 = {(__bf16)v0.x, (__bf16)v0.z, (__bf16)v0.w, (__bf16)v1.x,
                   (__bf16)v1.y, (__bf16)v1.z, (__bf16)v1.w, (__bf16)v2.x};
      bf16x8 q1 = {(__bf16)v2.y, (__bf16)v2.z, (__bf16)v2.w, (__bf16)v3.x,
                   (__bf16)v3.y, (__bf16)v3.z, (__bf16)v3.w, (__bf16)v4.x};
      bf16x8 q2 = {(__bf16)v4.y, (__bf16)v4.z, (__bf16)v4.w, (__bf16)e.x,
                   (__bf16)e.y,  (__bf16)e.z,  (__bf16)e.w,  (__bf16)0.f};
      *(bf16x8*)(d)      = q0;
      *(bf16x8*)(d + 8)  = q1;
      *(bf16x8*)(d + 16) = q2;
      *(bf16x8*)(d + 24) = zf;
    }
  };
  stageX(0);
  __syncthreads();

  if (w == 0) {
    // ---------------- L0: x(23) -> 64 units, 4 N-tiles ----------------
    bf16x8 WzX[4], WrX[4], WxX[4];
    f32x4 bZ[4], bR[4], bXH[4], bHH[4];
#pragma unroll
    for (int sl = 0; sl < 4; ++sl) {
      const int u = sl * 16 + c;
      WzX[sl] = bfragW(k0, 23, 192, u, kb);
      WrX[sl] = bfragW(k0, 23, 192, 64 + u, kb);
      WxX[sl] = bfragW(k0, 23, 192, 128 + u, kb);
      float vz = b0[u] + b0[192 + u];
      float vr = b0[64 + u] + b0[192 + 64 + u];
      float vx = b0[128 + u];
      float vh = b0[192 + 128 + u];
      bZ[sl]  = (f32x4){vz, vz, vz, vz};
      bR[sl]  = (f32x4){vr, vr, vr, vr};
      bXH[sl] = (f32x4){vx, vx, vx, vx};
      bHH[sl] = (f32x4){vh, vh, vh, vh};
    }
    f32x4 az[4], ar[4], ax[4], ah[4];
    float hp[4][4];
#pragma unroll
    for (int sl = 0; sl < 4; ++sl)
#pragma unroll
      for (int r = 0; r < 4; ++r) hp[sl][r] = 0.f;

    auto mfmaS = [&](int t) {
      bf16x8 Ax = *(const bf16x8*)&xring[(t & 15) * XPL + c * XSTR + kb];
#pragma unroll
      for (int sl = 0; sl < 4; ++sl) {
        az[sl] = mfma16(Ax, WzX[sl], bZ[sl]);
        ar[sl] = mfma16(Ax, WrX[sl], bR[sl]);
        ax[sl] = mfma16(Ax, WxX[sl], bXH[sl]);
      }
      const __bf16* hb = &h0ring[((t - 1) & 15) * H0PL + c * H0STR];
      bf16x8 Ah1 = *(const bf16x8*)&hb[kb];
      bf16x8 Ah2 = *(const bf16x8*)&hb[32 + kb];
      const __bf16* wp = &w0p[c * H0STR + kb];
#pragma unroll
      for (int sl = 0; sl < 4; ++sl) {
        bf16x8 f1 = *(const bf16x8*)&wp[sl * W0PL];
        bf16x8 f2 = *(const bf16x8*)&wp[sl * W0PL + 32];
        az[sl] = mfma16(Ah1, f1, az[sl]);
        az[sl] = mfma16(Ah2, f2, az[sl]);
      }
#pragma unroll
      for (int sl = 0; sl < 4; ++sl) {
        bf16x8 f1 = *(const bf16x8*)&wp[(4 + sl) * W0PL];
        bf16x8 f2 = *(const bf16x8*)&wp[(4 + sl) * W0PL + 32];
        ar[sl] = mfma16(Ah1, f1, ar[sl]);
        ar[sl] = mfma16(Ah2, f2, ar[sl]);
      }
#pragma unroll
      for (int sl = 0; sl < 4; ++sl) {
        bf16x8 f1 = *(const bf16x8*)&wp[(8 + sl) * W0PL];
        bf16x8 f2 = *(const bf16x8*)&wp[(8 + sl) * W0PL + 32];
        ah[sl] = mfma16(Ah1, f1, bHH[sl]);
        ah[sl] = mfma16(Ah2, f2, ah[sl]);
      }
    };
    auto gateS = [&](int t) {
      __bf16* wr = &h0ring[(t & 15) * H0PL + rq * H0STR];
#pragma unroll
      for (int sl = 0; sl < 4; ++sl)
#pragma unroll
        for (int r = 0; r < 4; ++r) {
          float z  = sigm(az[sl][r]);
          float rg = sigm(ar[sl][r]);
          float hc = tanh_(fmaf(rg, ah[sl][r], ax[sl][r]));
          float hn = fmaf(z, hp[sl][r] - hc, hc);
          hp[sl][r] = hn;
          wr[r * H0STR + sl * 16 + c] = (__bf16)hn;
        }
    };

    for (int sg = 0; sg < NSUP; ++sg) {
      const int tb = sg * KS;
      if (tb < TT) {
        mfmaS(tb);
#pragma unroll 1
        for (int k2 = 0; k2 < KS - 1; ++k2) {
          gateS(tb + k2);
          mfmaS(tb + k2 + 1);
        }
        gateS(tb + KS - 1);   // close the block BEFORE the barrier
      }
      __syncthreads();
    }
  } else if (w == 1) {
    // ---------------- L1: h0(64) -> 32 units, 2 N-tiles ----------------
    bf16x8 Wz1[2], Wz2[2], WzH[2], Wr1[2], Wr2[2], WrH[2], Wx1[2], Wx2[2], WhH[2];
    f32x4 bZ[2], bR[2], bXH[2], bHH[2];
#pragma unroll
    for (int t2 = 0; t2 < 2; ++t2) {
      const int u = t2 * 16 + c;
      Wz1[t2] = bfragW(k1, 64, 96, u, kb);
      Wz2[t2] = bfragW(k1, 64, 96, u, 32 + kb);
      WzH[t2] = bfragW(rk1, 32, 96, u, kb);
      Wr1[t2] = bfragW(k1, 64, 96, 32 + u, kb);
      Wr2[t2] = bfragW(k1, 64, 96, 32 + u, 32 + kb);
      WrH[t2] = bfragW(rk1, 32, 96, 32 + u, kb);
      Wx1[t2] = bfragW(k1, 64, 96, 64 + u, kb);
      Wx2[t2] = bfragW(k1, 64, 96, 64 + u, 32 + kb);
      WhH[t2] = bfragW(rk1, 32, 96, 64 + u, kb);
      float vz = b1[u] + b1[96 + u];
      float vr = b1[32 + u] + b1[96 + 32 + u];
      float vx = b1[64 + u];
      float vh = b1[96 + 64 + u];
      bZ[t2]  = (f32x4){vz, vz, vz, vz};
      bR[t2]  = (f32x4){vr, vr, vr, vr};
      bXH[t2] = (f32x4){vx, vx, vx, vx};
      bHH[t2] = (f32x4){vh, vh, vh, vh};
    }
    f32x4 az[2], ar[2], ax[2], ah[2];
    float hp[2][4];
#pragma unroll
    for (int t2 = 0; t2 < 2; ++t2)
#pragma unroll
      for (int r = 0; r < 4; ++r) hp[t2][r] = 0.f;

    auto mfmaS = [&](int t) {
      const __bf16* xb = &h0ring[(t & 15) * H0PL + c * H0STR];
      bf16x8 Ax1 = *(const bf16x8*)&xb[kb];
      bf16x8 Ax2 = *(const bf16x8*)&xb[32 + kb];
      bf16x8 Ah  = *(const bf16x8*)&h1ring[((t - 1) & 15) * H1PL + c * H1STR + kb];
#pragma unroll
      for (int t2 = 0; t2 < 2; ++t2) {
        az[t2] = mfma16(Ax1, Wz1[t2], bZ[t2]);
        az[t2] = mfma16(Ax2, Wz2[t2], az[t2]);
        az[t2] = mfma16(Ah,  WzH[t2], az[t2]);
        ar[t2] = mfma16(Ax1, Wr1[t2], bR[t2]);
        ar[t2] = mfma16(Ax2, Wr2[t2], ar[t2]);
        ar[t2] = mfma16(Ah,  WrH[t2], ar[t2]);
        ax[t2] = mfma16(Ax1, Wx1[t2], bXH[t2]);
        ax[t2] = mfma16(Ax2, Wx2[t2], ax[t2]);
        ah[t2] = mfma16(Ah,  WhH[t2], bHH[t2]);
      }
    };
    auto gateS = [&](int t) {
      __bf16* wr = &h1ring[(t & 15) * H1PL + rq * H1STR];
#pragma unroll
      for (int t2 = 0; t2 < 2; ++t2)
#pragma unroll
        for (int r = 0; r < 4; ++r) {
          float z  = sigm(az[t2][r]);
          float rg = sigm(ar[t2][r]);
          float hc = tanh_(fmaf(rg, ah[t2][r], ax[t2][r]));
          float hn = fmaf(z, hp[t2][r] - hc, hc);
          hp[t2][r] = hn;
          wr[r * H1STR + t2 * 16 + c] = (__bf16)hn;
        }
    };

    for (int sg = 0; sg < NSUP; ++sg) {
      const int tb = (sg - 1) * KS;
      if (tb >= 0 && tb < TT) {
        mfmaS(tb);
#pragma unroll 1
        for (int k2 = 0; k2 < KS - 1; ++k2) {
          gateS(tb + k2);
          mfmaS(tb + k2 + 1);
        }
        gateS(tb + KS - 1);
      }
      __syncthreads();
    }
  } else if (w == 2) {
    // ---------------- L2: h1(32) -> 32 units ----------------
    bf16x8 WzX[2], WzH[2], WrX[2], WrH[2], WxX[2], WhH[2];
    f32x4 bZ[2], bR[2], bXH[2], bHH[2];
#pragma unroll
    for (int t2 = 0; t2 < 2; ++t2) {
      const int u = t2 * 16 + c;
      WzX[t2] = bfragW(k2, 32, 96, u, kb);
      WzH[t2] = bfragW(rk2, 32, 96, u, kb);
      WrX[t2] = bfragW(k2, 32, 96, 32 + u, kb);
      WrH[t2] = bfragW(rk2, 32, 96, 32 + u, kb);
      WxX[t2] = bfragW(k2, 32, 96, 64 + u, kb);
      WhH[t2] = bfragW(rk2, 32, 96, 64 + u, kb);
      float vz = b2[u] + b2[96 + u];
      float vr = b2[32 + u] + b2[96 + 32 + u];
      float vx = b2[64 + u];
      float vh = b2[96 + 64 + u];
      bZ[t2]  = (f32x4){vz, vz, vz, vz};
      bR[t2]  = (f32x4){vr, vr, vr, vr};
      bXH[t2] = (f32x4){vx, vx, vx, vx};
      bHH[t2] = (f32x4){vh, vh, vh, vh};
    }
    f32x4 az[2], ar[2], ax[2], ah[2];
    float hp[2][4];
#pragma unroll
    for (int t2 = 0; t2 < 2; ++t2)
#pragma unroll
      for (int r = 0; r < 4; ++r) hp[t2][r] = 0.f;

    auto mfmaS = [&](int t) {
      bf16x8 Ax = *(const bf16x8*)&h1ring[(t & 15) * H1PL + c * H1STR + kb];
      bf16x8 Ah = *(const bf16x8*)&h2ring[((t - 1) & 15) * H1PL + c * H1STR + kb];
#pragma unroll
      for (int t2 = 0; t2 < 2; ++t2) {
        az[t2] = mfma16(Ax, WzX[t2], bZ[t2]);
        az[t2] = mfma16(Ah, WzH[t2], az[t2]);
        ar[t2] = mfma16(Ax, WrX[t2], bR[t2]);
        ar[t2] = mfma16(Ah, WrH[t2], ar[t2]);
        ax[t2] = mfma16(Ax, WxX[t2], bXH[t2]);
        ah[t2] = mfma16(Ah, WhH[t2], bHH[t2]);
      }
    };
    auto gateS = [&](int t) {
      __bf16* wr = &h2ring[(t & 15) * H1PL + rq * H1STR];
#pragma unroll
      for (int t2 = 0; t2 < 2; ++t2)
#pragma unroll
        for (int r = 0; r < 4; ++r) {
          float z  = sigm(az[t2][r]);
          float rg = sigm(ar[t2][r]);
          float hc = tanh_(fmaf(rg, ah[t2][r], ax[t2][r]));
          float hn = fmaf(z, hp[t2][r] - hc, hc);
          hp[t2][r] = hn;
          wr[r * H1STR + t2 * 16 + c] = (__bf16)hn;
        }
    };

    for (int sg = 0; sg < NSUP; ++sg) {
      const int tb = (sg - 2) * KS;
      if (tb >= 0 && tb < TT) {
        mfmaS(tb);
#pragma unroll 1
        for (int k2 = 0; k2 < KS - 1; ++k2) {
          gateS(tb + k2);
          mfmaS(tb + k2 + 1);
        }
        gateS(tb + KS - 1);
      }
      if (sg < 31) stageX((sg + 1) * KS);
      __syncthreads();
    }
  } else {
    // ---------------- L3: h2(32) -> 32 units ----------------
    bf16x8 WzX[2], WzH[2], WrX[2], WrH[2], WxX[2], WhH[2];
    f32x4 bZ[2], bR[2], bXH[2], bHH[2];
#pragma unroll
    for (int t2 = 0; t2 < 2; ++t2) {
      const int u = t2 * 16 + c;
      WzX[t2] = bfragW(k3, 32, 96, u, kb);
      WzH[t2] = bfragW(rk3, 32, 96, u, kb);
      WrX[t2] = bfragW(k3, 32, 96, 32 + u, kb);
      WrH[t2] = bfragW(rk3, 32, 96, 32 + u, kb);
      WxX[t2] = bfragW(k3, 32, 96, 64 + u, kb);
      WhH[t2] = bfragW(rk3, 32, 96, 64 + u, kb);
      float vz = b3[u] + b3[96 + u];
      float vr = b3[32 + u] + b3[96 + 32 + u];
      float vx = b3[64 + u];
      float vh = b3[96 + 64 + u];
      bZ[t2]  = (f32x4){vz, vz, vz, vz};
      bR[t2]  = (f32x4){vr, vr, vr, vr};
      bXH[t2] = (f32x4){vx, vx, vx, vx};
      bHH[t2] = (f32x4){vh, vh, vh, vh};
    }
    f32x4 az[2], ar[2], ax[2], ah[2];
    float hp[2][4];
#pragma unroll
    for (int t2 = 0; t2 < 2; ++t2)
#pragma unroll
      for (int r = 0; r < 4; ++r) hp[t2][r] = 0.f;

    auto mfmaS = [&](int t) {
      bf16x8 Ax = *(const bf16x8*)&h2ring[(t & 15) * H1PL + c * H1STR + kb];
      bf16x8 Ah = *(const bf16x8*)&h3s[((t - 1) & 1) * H1PL + c * H1STR + kb];
#pragma unroll
      for (int t2 = 0; t2 < 2; ++t2) {
        az[t2] = mfma16(Ax, WzX[t2], bZ[t2]);
        az[t2] = mfma16(Ah, WzH[t2], az[t2]);
        ar[t2] = mfma16(Ax, WrX[t2], bR[t2]);
        ar[t2] = mfma16(Ah, WrH[t2], ar[t2]);
        ax[t2] = mfma16(Ax, WxX[t2], bXH[t2]);
        ah[t2] = mfma16(Ah, WhH[t2], bHH[t2]);
      }
    };
    auto gateS = [&](int t) {
      __bf16* wr = &h3s[(t & 1) * H1PL + rq * H1STR];
#pragma unroll
      for (int t2 = 0; t2 < 2; ++t2)
#pragma unroll
        for (int r = 0; r < 4; ++r) {
          float z  = sigm(az[t2][r]);
          float rg = sigm(ar[t2][r]);
          float hc = tanh_(fmaf(rg, ah[t2][r], ax[t2][r]));
          float hn = fmaf(z, hp[t2][r] - hc, hc);
          hp[t2][r] = hn;
          wr[r * H1STR + t2 * 16 + c] = (__bf16)hn;
        }
    };

    for (int sg = 0; sg < NSUP; ++sg) {
      const int tb = (sg - 3) * KS;
      if (tb >= 0 && tb < TT) {
        mfmaS(tb);
#pragma unroll 1
        for (int k2 = 0; k2 < KS - 1; ++k2) {
          gateS(tb + k2);
          mfmaS(tb + k2 + 1);
        }
        gateS(tb + KS - 1);
      }
      if (sg < 31) stageX((sg + 1) * KS);
      __syncthreads();
    }

    // final h3(255) lives in hp registers -> stage for the softmax
#pragma unroll
    for (int t2 = 0; t2 < 2; ++t2)
#pragma unroll
      for (int r = 0; r < 4; ++r)
        h3f[(rq + r) * 32 + t2 * 16 + c] = hp[t2][r];
  }

  // ------------- epilogue: logits + softmax -------------
  __syncthreads();
  if (tid < BT) {
    float l0 = bd[0], l1 = bd[1];
#pragma unroll
    for (int u = 0; u < 32; ++u) {
      float h = h3f[tid * 32 + u];
      l0 = fmaf(h, Wd[2 * u], l0);
      l1 = fmaf(h, Wd[2 * u + 1], l1);
    }
    float m = fmaxf(l0, l1);
    float e0 = __builtin_amdgcn_exp2f((l0 - m) * 1.44269504f);
    float e1 = __builtin_amdgcn_exp2f((l1 - m) * 1.44269504f);
    float inv = 1.f / (e0 + e1);
    out[(bbase + tid) * 2 + 0] = e0 * inv;
    out[(bbase + tid) * 2 + 1] = e1 * inv;
  }
}

extern "C" void kernel_launch(void* const* d_in, const int* in_sizes, int n_in,
                              void* d_out, int out_size, void* d_ws, size_t ws_size,
                              hipStream_t stream) {
  const float* inp  = (const float*)d_in[0];
  const float* Wemb = (const float*)d_in[1];
  const float* k0   = (const float*)d_in[2];
  const float* rk0  = (const float*)d_in[3];
  const float* b0   = (const float*)d_in[4];
  const float* k1   = (const float*)d_in[5];
  const float* rk1  = (const float*)d_in[6];
  const float* b1   = (const float*)d_in[7];
  const float* k2   = (const float*)d_in[8];
  const float* rk2  = (const float*)d_in[9];
  const float* b2   = (const float*)d_in[10];
  const float* k3   = (const float*)d_in[11];
  const float* rk3  = (const float*)d_in[12];
  const float* b3   = (const float*)d_in[13];
  const float* Wd   = (const float*)d_in[14];
  const float* bd   = (const float*)d_in[15];
  float* out = (float*)d_out;

  const int Btot = in_sizes[0] / (TT * FF);   // 4096
  dim3 grid(Btot / BT);                       // 256 blocks
  gru4<<<grid, NTHR, 0, stream>>>(inp, Wemb, k0, rk0, b0, k1, rk1, b1,
                                  k2, rk2, b2, k3, rk3, b3, Wd, bd, out);
}

// Round 4
// 373.707 us; speedup vs baseline: 1.1924x; 1.1924x over previous
//
#include <hip/hip_runtime.h>

// 4-layer GRU stack, B=4096, T=256. 256 persistent blocks x 768 threads
// (12 waves, 3 per SIMD), 16 batch rows per block (one M=16 MFMA tile).
//
// Round-0 proven structure (per-SIMD balanced jobs, uniform MFMA shape)
// with per-step s_barrier replaced by point-to-point LDS counter sync.
// Counters advance in LAYER-LOCAL time t = s - lay (round-3 bug: used
// global s-1 -> off-by-lay races + cap-masked deadlocks).
//   g[l] = gate completions of layer l (nOwn signals per local step)
//   m[l] = A-frag read completions of layer l
// Wave of layer l at local step t:
//   before below-layer h reads: POLL(g[l-1] >= n_{l-1}*(t+1))
//   before own-recurrence reads: POLL(g[l]  >= n_l*t)
//   before gate writes (WAR):    POLL(m[l]  >= n_l*t)
//                                POLL(m[l+1]>= n_{l+1}*(t-1))
// Sum-counters are exact: a wave's progress past t is gated by the same
// counter, so intra-layer lockstep is self-enforcing (no straggler
// masking). Signals: lgkmcnt(0) then ds_add from lane 0.
// Real barriers only around bulk x staging (2 per 64 steps).
// Biases ride the first MFMA's C operand.
// Arithmetic is bit-identical to round-0 -> absmax must be 0.00390625.

typedef __attribute__((ext_vector_type(8))) __bf16 bf16x8;
typedef __attribute__((ext_vector_type(4))) float f32x4;

#define TT 256
#define FF 20
#define BT 16
#define CH 64      // x chunk steps held in LDS
#define SH0 72     // h0 LDS row stride (bf16), padded from 64
#define SH1 40     // h1/h2/h3 LDS row stride, padded from 32
#define XSTR 648   // x_ch t-plane stride (bf16): 16*40 + 8 pad
#define NTHR 768

__device__ __forceinline__ f32x4 mfma16(bf16x8 a, bf16x8 b, f32x4 c) {
  return __builtin_amdgcn_mfma_f32_16x16x32_bf16(a, b, c, 0, 0, 0);
}

// NaN-free, clamp-free: correct limits at +-inf (rcp(inf)=0).
__device__ __forceinline__ float sigm(float x) {
  return __builtin_amdgcn_rcpf(1.f + __builtin_amdgcn_exp2f(-1.44269504f * x));
}
__device__ __forceinline__ float tanh_(float x) {
  return __builtin_amdgcn_rcpf(1.f + __builtin_amdgcn_exp2f(-2.88539008f * x)) * 2.f - 1.f;
}

// B-operand fragment from global row-major W[K][N]: lane holds col n, k=kbase+j.
__device__ __forceinline__ bf16x8 bfragW(const float* W, int Kreal, int N,
                                         int ncol, int kbase) {
  bf16x8 r;
#pragma unroll
  for (int j = 0; j < 8; ++j) {
    int k = kbase + j;
    r[j] = (__bf16)(k < Kreal ? W[k * N + ncol] : 0.f);
  }
  return r;
}

// Spin until LDS counter *cptr >= tgt (targets <= 0 pass immediately).
// All 64 lanes read the same address (broadcast). sched_barrier + memory
// clobber fence subsequent LDS reads from hoisting above the poll.
#define POLL(cptr, tgt) { \
    while (*(volatile int*)(cptr) < (tgt)) {} \
    __builtin_amdgcn_sched_barrier(0); \
    asm volatile("" ::: "memory"); }

// Ensure all prior LDS ops of this wave completed, then bump the counter.
#define SIGNAL(cptr) { \
    asm volatile("s_waitcnt lgkmcnt(0)" ::: "memory"); \
    if (lane == 0) atomicAdd((int*)(cptr), 1); }

extern "C" __global__ void __launch_bounds__(NTHR, 3)
gru4(const float* __restrict__ inp, const float* __restrict__ Wemb,
     const float* __restrict__ k0, const float* __restrict__ rk0, const float* __restrict__ b0,
     const float* __restrict__ k1, const float* __restrict__ rk1, const float* __restrict__ b1,
     const float* __restrict__ k2, const float* __restrict__ rk2, const float* __restrict__ b2,
     const float* __restrict__ k3, const float* __restrict__ rk3, const float* __restrict__ b3,
     const float* __restrict__ Wd, const float* __restrict__ bd,
     float* __restrict__ out)
{
  __shared__ __align__(16) __bf16 x_ch[CH * XSTR];       // ~83 KB
  __shared__ __align__(16) __bf16 h0_lds[2][BT * SH0];
  __shared__ __align__(16) __bf16 h1_lds[2][BT * SH1];
  __shared__ __align__(16) __bf16 h2_lds[2][BT * SH1];
  __shared__ __align__(16) __bf16 h3_lds[2][BT * SH1];
  __shared__ __align__(16) float h3f[BT * 32];
  __shared__ int cnts[8];   // g0..g3 = cnts[0..3], m0..m3 = cnts[4..7]

  const int tid  = threadIdx.x;
  const int lane = tid & 63;
  const int w    = tid >> 6;        // wave 0..11
  const int col  = lane & 15;       // C col / B n / A m index
  const int kb   = (lane >> 4) * 8; // A/B k base within a k-tile
  const int rowq = (lane >> 4) * 4; // C row base (batch)
  const long bbase = (long)blockIdx.x * BT;
  const float* binp = inp + bbase * TT * FF;

  bf16x8 zf;
#pragma unroll
  for (int j = 0; j < 8; ++j) zf[j] = (__bf16)0.f;

  // ---- uniform per-wave job config (shared variables across all roles) ----
  bf16x8 Wz0 = zf, Wz1 = zf, Wz2 = zf;
  bf16x8 Wr0 = zf, Wr1 = zf, Wr2 = zf;
  bf16x8 Wgx0 = zf, Wgx1 = zf, Wgx2 = zf;
  bf16x8 Wgh0 = zf, Wgh1 = zf, Wgh2 = zf;
  float bz = 0.f, br = 0.f, bxh = 0.f, bhh = 0.f;
  const __bf16 *A0b = x_ch, *A1b = x_ch, *A2b = x_ch;
  int D0 = 0, D1 = 0, D2 = 0;
  __bf16* Wwr0 = (__bf16*)h3f;
  int WD = 0, wstride = SH1;
  int lay = 0;
  bool doLo = false, doHi = false, threeA = false;
  int* gBelow = (int*)&cnts[0]; int nBelow = 0;
  int* gOwn   = (int*)&cnts[0]; int nOwn   = 0;
  int* mOwn   = (int*)&cnts[4];
  int* mAbove = (int*)&cnts[4]; int nAbove = 0;

  if (w < 6) {
    // L0: w0..w3 = row-halves of slices 0,1; w4,w5 = full slices 2,3.
    lay = 0; threeA = true;
    const int sl = (w < 4) ? (w >> 1) : (w - 2);
    doLo = (w >= 4) || ((w & 1) == 0);
    doHi = (w >= 4) || ((w & 1) == 1);
    const int u = sl * 16 + col;
    Wz0 = bfragW(k0, 23, 192, u, kb);
    Wz1 = bfragW(rk0, 64, 192, u, kb);
    Wz2 = bfragW(rk0, 64, 192, u, 32 + kb);
    Wr0 = bfragW(k0, 23, 192, 64 + u, kb);
    Wr1 = bfragW(rk0, 64, 192, 64 + u, kb);
    Wr2 = bfragW(rk0, 64, 192, 64 + u, 32 + kb);
    Wgx0 = bfragW(k0, 23, 192, 128 + u, kb);
    Wgh1 = bfragW(rk0, 64, 192, 128 + u, kb);
    Wgh2 = bfragW(rk0, 64, 192, 128 + u, 32 + kb);
    bz  = b0[u] + b0[192 + u];
    br  = b0[64 + u] + b0[192 + 64 + u];
    bxh = b0[128 + u];
    bhh = b0[192 + 128 + u];
    A1b = &h0_lds[0][col * SH0 + kb];      D1 = BT * SH0;
    A2b = &h0_lds[0][col * SH0 + 32 + kb]; D2 = BT * SH0;
    Wwr0 = &h0_lds[0][rowq * SH0 + sl * 16 + col];
    WD = BT * SH0; wstride = SH0;
    gOwn = (int*)&cnts[0]; nOwn = 6;
    mOwn = (int*)&cnts[4];
    mAbove = (int*)&cnts[5]; nAbove = 2;
  } else if (w < 8) {
    // L1: slices 0,1 full.
    lay = 1; threeA = true; doLo = doHi = true;
    const int u = (w - 6) * 16 + col;
    Wz0 = bfragW(k1, 64, 96, u, kb);
    Wz1 = bfragW(k1, 64, 96, u, 32 + kb);
    Wz2 = bfragW(rk1, 32, 96, u, kb);
    Wr0 = bfragW(k1, 64, 96, 32 + u, kb);
    Wr1 = bfragW(k1, 64, 96, 32 + u, 32 + kb);
    Wr2 = bfragW(rk1, 32, 96, 32 + u, kb);
    Wgx0 = bfragW(k1, 64, 96, 64 + u, kb);
    Wgx1 = bfragW(k1, 64, 96, 64 + u, 32 + kb);
    Wgh2 = bfragW(rk1, 32, 96, 64 + u, kb);
    bz  = b1[u] + b1[96 + u];
    br  = b1[32 + u] + b1[96 + 32 + u];
    bxh = b1[64 + u];
    bhh = b1[96 + 64 + u];
    A0b = &h0_lds[0][col * SH0 + kb];      D0 = BT * SH0;
    A1b = &h0_lds[0][col * SH0 + 32 + kb]; D1 = BT * SH0;
    A2b = &h1_lds[0][col * SH1 + kb];      D2 = BT * SH1;
    Wwr0 = &h1_lds[0][rowq * SH1 + (w - 6) * 16 + col];
    WD = BT * SH1; wstride = SH1;
    gBelow = (int*)&cnts[0]; nBelow = 6;
    gOwn = (int*)&cnts[1]; nOwn = 2;
    mOwn = (int*)&cnts[5];
    mAbove = (int*)&cnts[6]; nAbove = 2;
  } else if (w < 10) {
    // L2: slices 0,1 full.
    lay = 2; threeA = false; doLo = doHi = true;
    const int u = (w - 8) * 16 + col;
    Wz0 = bfragW(k2, 32, 96, u, kb);
    Wz1 = bfragW(rk2, 32, 96, u, kb);
    Wr0 = bfragW(k2, 32, 96, 32 + u, kb);
    Wr1 = bfragW(rk2, 32, 96, 32 + u, kb);
    Wgx0 = bfragW(k2, 32, 96, 64 + u, kb);
    Wgh1 = bfragW(rk2, 32, 96, 64 + u, kb);
    bz  = b2[u] + b2[96 + u];
    br  = b2[32 + u] + b2[96 + 32 + u];
    bxh = b2[64 + u];
    bhh = b2[96 + 64 + u];
    A0b = &h1_lds[0][col * SH1 + kb]; D0 = BT * SH1;
    A1b = &h2_lds[0][col * SH1 + kb]; D1 = BT * SH1;
    A2b = A1b; D2 = D1;
    Wwr0 = &h2_lds[0][rowq * SH1 + (w - 8) * 16 + col];
    WD = BT * SH1; wstride = SH1;
    gBelow = (int*)&cnts[1]; nBelow = 2;
    gOwn = (int*)&cnts[2]; nOwn = 2;
    mOwn = (int*)&cnts[6];
    mAbove = (int*)&cnts[7]; nAbove = 2;
  } else {
    // L3: slices 0,1 full.
    lay = 3; threeA = false; doLo = doHi = true;
    const int u = (w - 10) * 16 + col;
    Wz0 = bfragW(k3, 32, 96, u, kb);
    Wz1 = bfragW(rk3, 32, 96, u, kb);
    Wr0 = bfragW(k3, 32, 96, 32 + u, kb);
    Wr1 = bfragW(rk3, 32, 96, 32 + u, kb);
    Wgx0 = bfragW(k3, 32, 96, 64 + u, kb);
    Wgh1 = bfragW(rk3, 32, 96, 64 + u, kb);
    bz  = b3[u] + b3[96 + u];
    br  = b3[32 + u] + b3[96 + 32 + u];
    bxh = b3[64 + u];
    bhh = b3[96 + 64 + u];
    A0b = &h2_lds[0][col * SH1 + kb]; D0 = BT * SH1;
    A1b = &h3_lds[0][col * SH1 + kb]; D1 = BT * SH1;
    A2b = A1b; D2 = D1;
    Wwr0 = &h3_lds[0][rowq * SH1 + (w - 10) * 16 + col];
    WD = BT * SH1; wstride = SH1;
    gBelow = (int*)&cnts[2]; nBelow = 2;
    gOwn = (int*)&cnts[3]; nOwn = 2;
    mOwn = (int*)&cnts[7];
  }

  // bias vectors ride the first MFMA's C operand
  const f32x4 BZ  = {bz, bz, bz, bz};
  const f32x4 BR  = {br, br, br, br};
  const f32x4 BXH = {bxh, bxh, bxh, bxh};
  const f32x4 BHH = {bhh, bhh, bhh, bhh};

  const __bf16* xb = &x_ch[col * 40 + kb];  // L0 x A-frag base (per t-plane)

  // ------------- zero-init h state + counters -------------
  {
    __bf16* p0 = (__bf16*)h0_lds;
    for (int i = tid; i < 2 * BT * SH0; i += NTHR) p0[i] = (__bf16)0.f;
    __bf16* p1 = (__bf16*)h1_lds;
    __bf16* p2 = (__bf16*)h2_lds;
    __bf16* p3 = (__bf16*)h3_lds;
    for (int i = tid; i < 2 * BT * SH1; i += NTHR) {
      p1[i] = (__bf16)0.f; p2[i] = (__bf16)0.f; p3[i] = (__bf16)0.f;
    }
    if (tid < 8) cnts[tid] = 0;
  }
  float hreg[4] = {0.f, 0.f, 0.f, 0.f};
  __syncthreads();

  // ---- bulk x staging every CH steps ----
  auto stageX = [&](int s) {
    for (int idx = tid; idx < BT * CH; idx += NTHR) {
      const int row = idx >> 6;          // CH = 64
      const int tg  = idx & (CH - 1);
      const float* p = binp + ((long)row * TT + s + tg) * FF;
      float4 v0 = *(const float4*)(p);
      float4 v1 = *(const float4*)(p + 4);
      float4 v2 = *(const float4*)(p + 8);
      float4 v3 = *(const float4*)(p + 12);
      float4 v4 = *(const float4*)(p + 16);
      float4 e  = *(const float4*)(Wemb + 4 * (int)v0.y);
      __bf16* d = &x_ch[tg * XSTR + row * 40];
      bf16x8 q0 = {(__bf16)v0.x, (__bf16)v0.z, (__bf16)v0.w, (__bf16)v1.x,
                   (__bf16)v1.y, (__bf16)v1.z, (__bf16)v1.w, (__bf16)v2.x};
      bf16x8 q1 = {(__bf16)v2.y, (__bf16)v2.z, (__bf16)v2.w, (__bf16)v3.x,
                   (__bf16)v3.y, (__bf16)v3.z, (__bf16)v3.w, (__bf16)v4.x};
      bf16x8 q2 = {(__bf16)v4.y, (__bf16)v4.z, (__bf16)v4.w, (__bf16)e.x,
                   (__bf16)e.y,  (__bf16)e.z,  (__bf16)e.w,  (__bf16)0.f};
      *(bf16x8*)(d)      = q0;
      *(bf16x8*)(d + 8)  = q1;
      *(bf16x8*)(d + 16) = q2;
      *(bf16x8*)(d + 24) = zf;
    }
  };

#define GATE(r) { \
    float z  = sigm(az[r]); \
    float rg = sigm(ar[r]); \
    float hc = tanh_(fmaf(rg, ahh[r], axh[r])); \
    float hn = fmaf(z, hreg[r] - hc, hc); \
    hreg[r] = hn; \
    wr[(r) * wstride] = (__bf16)hn; }

  for (int s = 0; s < TT + 3; ++s) {
    // ---- bulk x staging every CH steps (only full-block syncs) ----
    if ((s & (CH - 1)) == 0 && s < TT) {
      __syncthreads();           // all waves done reading previous chunk
      stageX(s);
      __syncthreads();           // staged planes visible
    }

    const int pb = (s + 1) & 1;  // read buffer (previous step's writes)
    const int qb = s & 1;        // write buffer
    const int t  = s - lay;      // LAYER-LOCAL time; counters scale with t

    if (t >= 0 && t < TT) {
      // -- stage 1: below-layer / x part (no own-recurrence dependency) --
      if (lay > 0) POLL(gBelow, nBelow * (t + 1));
      const __bf16* a0p = (lay == 0) ? (xb + (s & (CH - 1)) * XSTR)
                                     : (A0b + pb * D0);
      bf16x8 A0 = *(const bf16x8*)a0p;
      f32x4 az  = mfma16(A0, Wz0, BZ);
      f32x4 ar  = mfma16(A0, Wr0, BR);
      f32x4 axh = mfma16(A0, Wgx0, BXH);
      f32x4 ahh = mfma16(A0, Wgh0, BHH);

      // -- stage 2: own-recurrence part --
      POLL(gOwn, nOwn * t);
      bf16x8 A1 = *(const bf16x8*)(A1b + pb * D1);
      az  = mfma16(A1, Wz1, az);
      ar  = mfma16(A1, Wr1, ar);
      axh = mfma16(A1, Wgx1, axh);
      ahh = mfma16(A1, Wgh1, ahh);
      if (threeA) {
        bf16x8 A2 = *(const bf16x8*)(A2b + pb * D2);
        az  = mfma16(A2, Wz2, az);
        ar  = mfma16(A2, Wr2, ar);
        axh = mfma16(A2, Wgx2, axh);
        ahh = mfma16(A2, Wgh2, ahh);
      }
      SIGNAL(mOwn);              // my A-frag LDS reads for local t are done

      // -- gate: WAR — readers of my write-buffer must finish local t-1 --
      POLL(mOwn, nOwn * t);
      if (lay < 3) POLL(mAbove, nAbove * (t - 1));
      __bf16* wr = Wwr0 + qb * WD;
      if (doLo) { GATE(0); GATE(1); }
      if (doHi) { GATE(2); GATE(3); }
      SIGNAL(gOwn);              // my h(t) writes are visible
    }
  }
#undef GATE

  // ------------- epilogue: logits + softmax -------------
  __syncthreads();
  if (w >= 10) {
#pragma unroll
    for (int r = 0; r < 4; ++r)
      h3f[(rowq + r) * 32 + (w - 10) * 16 + col] = hreg[r];
  }
  __syncthreads();

  if (tid < BT) {
    float l0 = bd[0], l1 = bd[1];
#pragma unroll
    for (int u = 0; u < 32; ++u) {
      float h = h3f[tid * 32 + u];
      l0 = fmaf(h, Wd[2 * u], l0);
      l1 = fmaf(h, Wd[2 * u + 1], l1);
    }
    float m = fmaxf(l0, l1);
    float e0 = __builtin_amdgcn_exp2f((l0 - m) * 1.44269504f);
    float e1 = __builtin_amdgcn_exp2f((l1 - m) * 1.44269504f);
    float inv = 1.f / (e0 + e1);
    out[(bbase + tid) * 2 + 0] = e0 * inv;
    out[(bbase + tid) * 2 + 1] = e1 * inv;
  }
}

extern "C" void kernel_launch(void* const* d_in, const int* in_sizes, int n_in,
                              void* d_out, int out_size, void* d_ws, size_t ws_size,
                              hipStream_t stream) {
  const float* inp  = (const float*)d_in[0];
  const float* Wemb = (const float*)d_in[1];
  const float* k0   = (const float*)d_in[2];
  const float* rk0  = (const float*)d_in[3];
  const float* b0   = (const float*)d_in[4];
  const float* k1   = (const float*)d_in[5];
  const float* rk1  = (const float*)d_in[6];
  const float* b1   = (const float*)d_in[7];
  const float* k2   = (const float*)d_in[8];
  const float* rk2  = (const float*)d_in[9];
  const float* b2   = (const float*)d_in[10];
  const float* k3   = (const float*)d_in[11];
  const float* rk3  = (const float*)d_in[12];
  const float* b3   = (const float*)d_in[13];
  const float* Wd   = (const float*)d_in[14];
  const float* bd   = (const float*)d_in[15];
  float* out = (float*)d_out;

  const int Btot = in_sizes[0] / (TT * FF);   // 4096
  dim3 grid(Btot / BT);                       // 256 blocks
  gru4<<<grid, NTHR, 0, stream>>>(inp, Wemb, k0, rk0, b0, k1, rk1, b1,
                                  k2, rk2, b2, k3, rk3, b3, Wd, bd, out);
}

// Round 5
// 358.128 us; speedup vs baseline: 1.2443x; 1.0435x over previous
//
#include <hip/hip_runtime.h>

// 4-layer GRU stack, B=4096, T=256. 256 persistent blocks x 1024 threads
// (16 waves, 4 per SIMD), 16 batch rows per block (one M=16 MFMA tile).
//
// Proven round-0 structure (per-step s_barrier, uniform MFMA job shape)
// with occupancy raised 12 -> 16 waves for latency hiding:
//   jobs = {L0: 4 slices x 2 row-halves (8 waves),
//           L1: 2 slices x 2 row-halves (4 waves),
//           L2: 2 full, L3: 2 full}              -> 16 jobs.
//   wave->SIMD = w%4 gives every SIMD {L0h, L0h, L1h, full}
//   = 12+12+12+24 = 60 transcendentals/step — exactly balanced.
// Half-jobs duplicate the slice's 12 MFMAs but gate half the C rows
// (MFMA pipe has headroom at 23% util; trans/VALU is the bottleneck).
//
// Biases ride the first MFMA's C operand (no per-step acc-init movs) —
// correctness of this variant verified in round 4 (absmax 0.00390625).
//
// Arithmetic is bit-identical to the 343 us baseline.

typedef __attribute__((ext_vector_type(8))) __bf16 bf16x8;
typedef __attribute__((ext_vector_type(4))) float f32x4;

#define TT 256
#define FF 20
#define BT 16
#define CH 64      // x chunk steps held in LDS
#define SH0 72     // h0 LDS row stride (bf16), padded from 64
#define SH1 40     // h1/h2/h3 LDS row stride, padded from 32
#define XSTR 648   // x_ch t-plane stride (bf16): 16*40 + 8 pad
#define NTHR 1024

__device__ __forceinline__ f32x4 mfma16(bf16x8 a, bf16x8 b, f32x4 c) {
  return __builtin_amdgcn_mfma_f32_16x16x32_bf16(a, b, c, 0, 0, 0);
}

// NaN-free, clamp-free: correct limits at +-inf (rcp(inf)=0).
__device__ __forceinline__ float sigm(float x) {
  return __builtin_amdgcn_rcpf(1.f + __builtin_amdgcn_exp2f(-1.44269504f * x));
}
__device__ __forceinline__ float tanh_(float x) {
  return __builtin_amdgcn_rcpf(1.f + __builtin_amdgcn_exp2f(-2.88539008f * x)) * 2.f - 1.f;
}

// B-operand fragment from global row-major W[K][N]: lane holds col n, k=kbase+j.
__device__ __forceinline__ bf16x8 bfragW(const float* W, int Kreal, int N,
                                         int ncol, int kbase) {
  bf16x8 r;
#pragma unroll
  for (int j = 0; j < 8; ++j) {
    int k = kbase + j;
    r[j] = (__bf16)(k < Kreal ? W[k * N + ncol] : 0.f);
  }
  return r;
}

extern "C" __global__ void __launch_bounds__(NTHR, 4)
gru4(const float* __restrict__ inp, const float* __restrict__ Wemb,
     const float* __restrict__ k0, const float* __restrict__ rk0, const float* __restrict__ b0,
     const float* __restrict__ k1, const float* __restrict__ rk1, const float* __restrict__ b1,
     const float* __restrict__ k2, const float* __restrict__ rk2, const float* __restrict__ b2,
     const float* __restrict__ k3, const float* __restrict__ rk3, const float* __restrict__ b3,
     const float* __restrict__ Wd, const float* __restrict__ bd,
     float* __restrict__ out)
{
  __shared__ __align__(16) __bf16 x_ch[CH * XSTR];       // ~83 KB
  __shared__ __align__(16) __bf16 h0_lds[2][BT * SH0];
  __shared__ __align__(16) __bf16 h1_lds[2][BT * SH1];
  __shared__ __align__(16) __bf16 h2_lds[2][BT * SH1];
  __shared__ __align__(16) __bf16 h3_lds[2][BT * SH1];
  __shared__ __align__(16) float h3f[BT * 32];

  const int tid  = threadIdx.x;
  const int lane = tid & 63;
  const int w    = tid >> 6;        // wave 0..15
  const int col  = lane & 15;       // C col / B n / A m index
  const int kb   = (lane >> 4) * 8; // A/B k base within a k-tile
  const int rowq = (lane >> 4) * 4; // C row base (batch)
  const long bbase = (long)blockIdx.x * BT;
  const float* binp = inp + bbase * TT * FF;

  bf16x8 zf;
#pragma unroll
  for (int j = 0; j < 8; ++j) zf[j] = (__bf16)0.f;

  // ---- uniform per-wave job config (shared variables across all roles) ----
  bf16x8 Wz0 = zf, Wz1 = zf, Wz2 = zf;
  bf16x8 Wr0 = zf, Wr1 = zf, Wr2 = zf;
  bf16x8 Wgx0 = zf, Wgx1 = zf, Wgx2 = zf;
  bf16x8 Wgh0 = zf, Wgh1 = zf, Wgh2 = zf;
  float bz = 0.f, br = 0.f, bxh = 0.f, bhh = 0.f;
  const __bf16 *A0b = x_ch, *A1b = x_ch, *A2b = x_ch;
  int D0 = 0, D1 = 0, D2 = 0;
  __bf16* Wwr0 = (__bf16*)h3f;
  int WD = 0, wstride = SH1;
  int lay = 0;
  bool doLo = false, doHi = false, threeA = false;

  if (w < 8) {
    // L0: 4 slices x 2 row-halves. sl = w>>1, half = w&1.
    lay = 0; threeA = true;
    const int sl = w >> 1;
    doLo = ((w & 1) == 0);
    doHi = ((w & 1) == 1);
    const int u = sl * 16 + col;
    Wz0 = bfragW(k0, 23, 192, u, kb);
    Wz1 = bfragW(rk0, 64, 192, u, kb);
    Wz2 = bfragW(rk0, 64, 192, u, 32 + kb);
    Wr0 = bfragW(k0, 23, 192, 64 + u, kb);
    Wr1 = bfragW(rk0, 64, 192, 64 + u, kb);
    Wr2 = bfragW(rk0, 64, 192, 64 + u, 32 + kb);
    Wgx0 = bfragW(k0, 23, 192, 128 + u, kb);
    Wgh1 = bfragW(rk0, 64, 192, 128 + u, kb);
    Wgh2 = bfragW(rk0, 64, 192, 128 + u, 32 + kb);
    bz  = b0[u] + b0[192 + u];
    br  = b0[64 + u] + b0[192 + 64 + u];
    bxh = b0[128 + u];
    bhh = b0[192 + 128 + u];
    A1b = &h0_lds[0][col * SH0 + kb];      D1 = BT * SH0;
    A2b = &h0_lds[0][col * SH0 + 32 + kb]; D2 = BT * SH0;
    Wwr0 = &h0_lds[0][rowq * SH0 + sl * 16 + col];
    WD = BT * SH0; wstride = SH0;
  } else if (w < 12) {
    // L1: 2 slices x 2 row-halves. sl = (w-8)>>1, half = w&1.
    lay = 1; threeA = true;
    const int sl = (w - 8) >> 1;
    doLo = ((w & 1) == 0);
    doHi = ((w & 1) == 1);
    const int u = sl * 16 + col;
    Wz0 = bfragW(k1, 64, 96, u, kb);
    Wz1 = bfragW(k1, 64, 96, u, 32 + kb);
    Wz2 = bfragW(rk1, 32, 96, u, kb);
    Wr0 = bfragW(k1, 64, 96, 32 + u, kb);
    Wr1 = bfragW(k1, 64, 96, 32 + u, 32 + kb);
    Wr2 = bfragW(rk1, 32, 96, 32 + u, kb);
    Wgx0 = bfragW(k1, 64, 96, 64 + u, kb);
    Wgx1 = bfragW(k1, 64, 96, 64 + u, 32 + kb);
    Wgh2 = bfragW(rk1, 32, 96, 64 + u, kb);
    bz  = b1[u] + b1[96 + u];
    br  = b1[32 + u] + b1[96 + 32 + u];
    bxh = b1[64 + u];
    bhh = b1[96 + 64 + u];
    A0b = &h0_lds[0][col * SH0 + kb];      D0 = BT * SH0;
    A1b = &h0_lds[0][col * SH0 + 32 + kb]; D1 = BT * SH0;
    A2b = &h1_lds[0][col * SH1 + kb];      D2 = BT * SH1;
    Wwr0 = &h1_lds[0][rowq * SH1 + sl * 16 + col];
    WD = BT * SH1; wstride = SH1;
  } else if (w < 14) {
    // L2: slices 0,1 full.
    lay = 2; threeA = false; doLo = doHi = true;
    const int u = (w - 12) * 16 + col;
    Wz0 = bfragW(k2, 32, 96, u, kb);
    Wz1 = bfragW(rk2, 32, 96, u, kb);
    Wr0 = bfragW(k2, 32, 96, 32 + u, kb);
    Wr1 = bfragW(rk2, 32, 96, 32 + u, kb);
    Wgx0 = bfragW(k2, 32, 96, 64 + u, kb);
    Wgh1 = bfragW(rk2, 32, 96, 64 + u, kb);
    bz  = b2[u] + b2[96 + u];
    br  = b2[32 + u] + b2[96 + 32 + u];
    bxh = b2[64 + u];
    bhh = b2[96 + 64 + u];
    A0b = &h1_lds[0][col * SH1 + kb]; D0 = BT * SH1;
    A1b = &h2_lds[0][col * SH1 + kb]; D1 = BT * SH1;
    A2b = A1b; D2 = D1;
    Wwr0 = &h2_lds[0][rowq * SH1 + (w - 12) * 16 + col];
    WD = BT * SH1; wstride = SH1;
  } else {
    // L3: slices 0,1 full.
    lay = 3; threeA = false; doLo = doHi = true;
    const int u = (w - 14) * 16 + col;
    Wz0 = bfragW(k3, 32, 96, u, kb);
    Wz1 = bfragW(rk3, 32, 96, u, kb);
    Wr0 = bfragW(k3, 32, 96, 32 + u, kb);
    Wr1 = bfragW(rk3, 32, 96, 32 + u, kb);
    Wgx0 = bfragW(k3, 32, 96, 64 + u, kb);
    Wgh1 = bfragW(rk3, 32, 96, 64 + u, kb);
    bz  = b3[u] + b3[96 + u];
    br  = b3[32 + u] + b3[96 + 32 + u];
    bxh = b3[64 + u];
    bhh = b3[96 + 64 + u];
    A0b = &h2_lds[0][col * SH1 + kb]; D0 = BT * SH1;
    A1b = &h3_lds[0][col * SH1 + kb]; D1 = BT * SH1;
    A2b = A1b; D2 = D1;
    Wwr0 = &h3_lds[0][rowq * SH1 + (w - 14) * 16 + col];
    WD = BT * SH1; wstride = SH1;
  }

  // bias vectors ride the first MFMA's C operand
  const f32x4 BZ  = {bz, bz, bz, bz};
  const f32x4 BR  = {br, br, br, br};
  const f32x4 BXH = {bxh, bxh, bxh, bxh};
  const f32x4 BHH = {bhh, bhh, bhh, bhh};

  const __bf16* xb = &x_ch[col * 40 + kb];  // L0 x A-frag base (per t-plane)

  // ------------- zero-init h state -------------
  {
    __bf16* p0 = (__bf16*)h0_lds;
    for (int i = tid; i < 2 * BT * SH0; i += NTHR) p0[i] = (__bf16)0.f;
    __bf16* p1 = (__bf16*)h1_lds;
    __bf16* p2 = (__bf16*)h2_lds;
    __bf16* p3 = (__bf16*)h3_lds;
    for (int i = tid; i < 2 * BT * SH1; i += NTHR) {
      p1[i] = (__bf16)0.f; p2[i] = (__bf16)0.f; p3[i] = (__bf16)0.f;
    }
  }
  float hreg[4] = {0.f, 0.f, 0.f, 0.f};
  __syncthreads();

#define GATE(r) { \
    float z  = sigm(az[r]); \
    float rg = sigm(ar[r]); \
    float hc = tanh_(fmaf(rg, ahh[r], axh[r])); \
    float hn = fmaf(z, hreg[r] - hc, hc); \
    hreg[r] = hn; \
    wr[(r) * wstride] = (__bf16)hn; }

  for (int s = 0; s < TT + 3; ++s) {
    // ---- bulk x staging every CH steps ----
    if ((s & (CH - 1)) == 0 && s < TT) {
      for (int idx = tid; idx < BT * CH; idx += NTHR) {
        const int row = idx >> 6;          // CH = 64
        const int tg  = idx & (CH - 1);
        const float* p = binp + ((long)row * TT + s + tg) * FF;
        float4 v0 = *(const float4*)(p);
        float4 v1 = *(const float4*)(p + 4);
        float4 v2 = *(const float4*)(p + 8);
        float4 v3 = *(const float4*)(p + 12);
        float4 v4 = *(const float4*)(p + 16);
        float4 e  = *(const float4*)(Wemb + 4 * (int)v0.y);
        __bf16* d = &x_ch[tg * XSTR + row * 40];
        bf16x8 q0 = {(__bf16)v0.x, (__bf16)v0.z, (__bf16)v0.w, (__bf16)v1.x,
                     (__bf16)v1.y, (__bf16)v1.z, (__bf16)v1.w, (__bf16)v2.x};
        bf16x8 q1 = {(__bf16)v2.y, (__bf16)v2.z, (__bf16)v2.w, (__bf16)v3.x,
                     (__bf16)v3.y, (__bf16)v3.z, (__bf16)v3.w, (__bf16)v4.x};
        bf16x8 q2 = {(__bf16)v4.y, (__bf16)v4.z, (__bf16)v4.w, (__bf16)e.x,
                     (__bf16)e.y,  (__bf16)e.z,  (__bf16)e.w,  (__bf16)0.f};
        *(bf16x8*)(d)      = q0;
        *(bf16x8*)(d + 8)  = q1;
        *(bf16x8*)(d + 16) = q2;
        *(bf16x8*)(d + 24) = zf;
      }
      __syncthreads();
    }

    const int pb = (s + 1) & 1;  // read buffer (previous step's writes)
    const int qb = s & 1;        // write buffer
    const int t  = s - lay;

    if (t >= 0 && t < TT) {
      const __bf16* a0p = (lay == 0) ? (xb + (s & (CH - 1)) * XSTR)
                                     : (A0b + pb * D0);
      bf16x8 A0 = *(const bf16x8*)a0p;
      bf16x8 A1 = *(const bf16x8*)(A1b + pb * D1);
      f32x4 az  = mfma16(A0, Wz0, BZ);
      f32x4 ar  = mfma16(A0, Wr0, BR);
      f32x4 axh = mfma16(A0, Wgx0, BXH);
      f32x4 ahh = mfma16(A0, Wgh0, BHH);
      az  = mfma16(A1, Wz1, az);
      ar  = mfma16(A1, Wr1, ar);
      axh = mfma16(A1, Wgx1, axh);
      ahh = mfma16(A1, Wgh1, ahh);
      if (threeA) {
        bf16x8 A2 = *(const bf16x8*)(A2b + pb * D2);
        az  = mfma16(A2, Wz2, az);
        ar  = mfma16(A2, Wr2, ar);
        axh = mfma16(A2, Wgx2, axh);
        ahh = mfma16(A2, Wgh2, ahh);
      }
      __bf16* wr = Wwr0 + qb * WD;

      if (doLo) { GATE(0); GATE(1); }
      if (doHi) { GATE(2); GATE(3); }
    }

    __syncthreads();   // single per-step barrier
  }
#undef GATE

  // ------------- epilogue: logits + softmax -------------
  if (w >= 14) {
#pragma unroll
    for (int r = 0; r < 4; ++r)
      h3f[(rowq + r) * 32 + (w - 14) * 16 + col] = hreg[r];
  }
  __syncthreads();

  if (tid < BT) {
    float l0 = bd[0], l1 = bd[1];
#pragma unroll
    for (int u = 0; u < 32; ++u) {
      float h = h3f[tid * 32 + u];
      l0 = fmaf(h, Wd[2 * u], l0);
      l1 = fmaf(h, Wd[2 * u + 1], l1);
    }
    float m = fmaxf(l0, l1);
    float e0 = __builtin_amdgcn_exp2f((l0 - m) * 1.44269504f);
    float e1 = __builtin_amdgcn_exp2f((l1 - m) * 1.44269504f);
    float inv = 1.f / (e0 + e1);
    out[(bbase + tid) * 2 + 0] = e0 * inv;
    out[(bbase + tid) * 2 + 1] = e1 * inv;
  }
}

extern "C" void kernel_launch(void* const* d_in, const int* in_sizes, int n_in,
                              void* d_out, int out_size, void* d_ws, size_t ws_size,
                              hipStream_t stream) {
  const float* inp  = (const float*)d_in[0];
  const float* Wemb = (const float*)d_in[1];
  const float* k0   = (const float*)d_in[2];
  const float* rk0  = (const float*)d_in[3];
  const float* b0   = (const float*)d_in[4];
  const float* k1   = (const float*)d_in[5];
  const float* rk1  = (const float*)d_in[6];
  const float* b1   = (const float*)d_in[7];
  const float* k2   = (const float*)d_in[8];
  const float* rk2  = (const float*)d_in[9];
  const float* b2   = (const float*)d_in[10];
  const float* k3   = (const float*)d_in[11];
  const float* rk3  = (const float*)d_in[12];
  const float* b3   = (const float*)d_in[13];
  const float* Wd   = (const float*)d_in[14];
  const float* bd   = (const float*)d_in[15];
  float* out = (float*)d_out;

  const int Btot = in_sizes[0] / (TT * FF);   // 4096
  dim3 grid(Btot / BT);                       // 256 blocks
  gru4<<<grid, NTHR, 0, stream>>>(inp, Wemb, k0, rk0, b0, k1, rk1, b1,
                                  k2, rk2, b2, k3, rk3, b3, Wd, bd, out);
}

// Round 6
// 342.574 us; speedup vs baseline: 1.3007x; 1.0454x over previous
//
#include <hip/hip_runtime.h>

// 4-layer GRU stack, B=4096, T=256. 256 persistent blocks x 768 threads
// (12 waves, 3 per SIMD), 16 batch rows per block (one M=16 MFMA tile).
// Round-0 proven structure (per-step s_barrier, per-SIMD balanced jobs:
// every SIMD gets {L0-half, full, full} jobs).
//
// This round: the kernel is transcendental-throughput bound (R5 showed
// VALUBusy pinned ~54% independent of wave count; 60 trans/SIMD/step at
// ~16cy dominate). Two reductions, no structural change:
//  1. Weights/biases PRE-SCALED by -log2e (z,r) and -2log2e (g gates) at
//     fragment build -> MFMA outputs are directly exp2 arguments
//     (kills 3 v_mul per gate-eval).
//  2. Single-division gate: with z=1/(1+ea), hc=(1-ec)/(1+ec),
//       hn = [h(1+ec) + ea(1-ec)] / [(1+ea)(1+ec)]
//     merges z-rcp and tanh-rcp -> 3 exp + 2 rcp per element (was 3+3).
//  Per gate-eval: ~120cy -> ~98cy of VALU busy.
// Biases ride the first MFMA's C operand (proven R4/R5).
// NOTE: arithmetic is reassociated vs baseline -> absmax will differ
// slightly from 0.00390625 (expected <= ~0.008, threshold 0.0107).

typedef __attribute__((ext_vector_type(8))) __bf16 bf16x8;
typedef __attribute__((ext_vector_type(4))) float f32x4;

#define TT 256
#define FF 20
#define BT 16
#define CH 64      // x chunk steps held in LDS
#define SH0 72     // h0 LDS row stride (bf16), padded from 64
#define SH1 40     // h1/h2/h3 LDS row stride, padded from 32
#define XSTR 648   // x_ch t-plane stride (bf16): 16*40 + 8 pad
#define NTHR 768

#define SZ (-1.44269504f)   // -log2(e): z/r gate pre-scale
#define SG (-2.88539008f)   // -2*log2(e): candidate-gate pre-scale

__device__ __forceinline__ f32x4 mfma16(bf16x8 a, bf16x8 b, f32x4 c) {
  return __builtin_amdgcn_mfma_f32_16x16x32_bf16(a, b, c, 0, 0, 0);
}

// B-operand fragment from global row-major W[K][N], pre-scaled.
__device__ __forceinline__ bf16x8 bfragW(const float* W, int Kreal, int N,
                                         int ncol, int kbase, float scale) {
  bf16x8 r;
#pragma unroll
  for (int j = 0; j < 8; ++j) {
    int k = kbase + j;
    r[j] = (__bf16)(k < Kreal ? scale * W[k * N + ncol] : 0.f);
  }
  return r;
}

extern "C" __global__ void __launch_bounds__(NTHR, 3)
gru4(const float* __restrict__ inp, const float* __restrict__ Wemb,
     const float* __restrict__ k0, const float* __restrict__ rk0, const float* __restrict__ b0,
     const float* __restrict__ k1, const float* __restrict__ rk1, const float* __restrict__ b1,
     const float* __restrict__ k2, const float* __restrict__ rk2, const float* __restrict__ b2,
     const float* __restrict__ k3, const float* __restrict__ rk3, const float* __restrict__ b3,
     const float* __restrict__ Wd, const float* __restrict__ bd,
     float* __restrict__ out)
{
  __shared__ __align__(16) __bf16 x_ch[CH * XSTR];       // ~83 KB
  __shared__ __align__(16) __bf16 h0_lds[2][BT * SH0];
  __shared__ __align__(16) __bf16 h1_lds[2][BT * SH1];
  __shared__ __align__(16) __bf16 h2_lds[2][BT * SH1];
  __shared__ __align__(16) __bf16 h3_lds[2][BT * SH1];
  __shared__ __align__(16) float h3f[BT * 32];

  const int tid  = threadIdx.x;
  const int lane = tid & 63;
  const int w    = tid >> 6;        // wave 0..11
  const int col  = lane & 15;       // C col / B n / A m index
  const int kb   = (lane >> 4) * 8; // A/B k base within a k-tile
  const int rowq = (lane >> 4) * 4; // C row base (batch)
  const long bbase = (long)blockIdx.x * BT;
  const float* binp = inp + bbase * TT * FF;

  bf16x8 zf;
#pragma unroll
  for (int j = 0; j < 8; ++j) zf[j] = (__bf16)0.f;

  // ---- uniform per-wave job config (shared variables across all roles) ----
  bf16x8 Wz0 = zf, Wz1 = zf, Wz2 = zf;
  bf16x8 Wr0 = zf, Wr1 = zf, Wr2 = zf;
  bf16x8 Wgx0 = zf, Wgx1 = zf, Wgx2 = zf;
  bf16x8 Wgh0 = zf, Wgh1 = zf, Wgh2 = zf;
  float bz = 0.f, br = 0.f, bxh = 0.f, bhh = 0.f;
  const __bf16 *A0b = x_ch, *A1b = x_ch, *A2b = x_ch;
  int D0 = 0, D1 = 0, D2 = 0;
  __bf16* Wwr0 = (__bf16*)h3f;
  int WD = 0, wstride = SH1;
  int lay = 0;
  bool doLo = false, doHi = false, threeA = false;

  if (w < 6) {
    // L0: w0..w3 = row-halves of slices 0,1; w4,w5 = full slices 2,3.
    lay = 0; threeA = true;
    const int sl = (w < 4) ? (w >> 1) : (w - 2);
    doLo = (w >= 4) || ((w & 1) == 0);
    doHi = (w >= 4) || ((w & 1) == 1);
    const int u = sl * 16 + col;
    Wz0 = bfragW(k0, 23, 192, u, kb, SZ);
    Wz1 = bfragW(rk0, 64, 192, u, kb, SZ);
    Wz2 = bfragW(rk0, 64, 192, u, 32 + kb, SZ);
    Wr0 = bfragW(k0, 23, 192, 64 + u, kb, SZ);
    Wr1 = bfragW(rk0, 64, 192, 64 + u, kb, SZ);
    Wr2 = bfragW(rk0, 64, 192, 64 + u, 32 + kb, SZ);
    Wgx0 = bfragW(k0, 23, 192, 128 + u, kb, SG);
    Wgh1 = bfragW(rk0, 64, 192, 128 + u, kb, SG);
    Wgh2 = bfragW(rk0, 64, 192, 128 + u, 32 + kb, SG);
    bz  = SZ * (b0[u] + b0[192 + u]);
    br  = SZ * (b0[64 + u] + b0[192 + 64 + u]);
    bxh = SG * b0[128 + u];
    bhh = SG * b0[192 + 128 + u];
    A1b = &h0_lds[0][col * SH0 + kb];      D1 = BT * SH0;
    A2b = &h0_lds[0][col * SH0 + 32 + kb]; D2 = BT * SH0;
    Wwr0 = &h0_lds[0][rowq * SH0 + sl * 16 + col];
    WD = BT * SH0; wstride = SH0;
  } else if (w < 8) {
    // L1: slices 0,1 full.
    lay = 1; threeA = true; doLo = doHi = true;
    const int u = (w - 6) * 16 + col;
    Wz0 = bfragW(k1, 64, 96, u, kb, SZ);
    Wz1 = bfragW(k1, 64, 96, u, 32 + kb, SZ);
    Wz2 = bfragW(rk1, 32, 96, u, kb, SZ);
    Wr0 = bfragW(k1, 64, 96, 32 + u, kb, SZ);
    Wr1 = bfragW(k1, 64, 96, 32 + u, 32 + kb, SZ);
    Wr2 = bfragW(rk1, 32, 96, 32 + u, kb, SZ);
    Wgx0 = bfragW(k1, 64, 96, 64 + u, kb, SG);
    Wgx1 = bfragW(k1, 64, 96, 64 + u, 32 + kb, SG);
    Wgh2 = bfragW(rk1, 32, 96, 64 + u, kb, SG);
    bz  = SZ * (b1[u] + b1[96 + u]);
    br  = SZ * (b1[32 + u] + b1[96 + 32 + u]);
    bxh = SG * b1[64 + u];
    bhh = SG * b1[96 + 64 + u];
    A0b = &h0_lds[0][col * SH0 + kb];      D0 = BT * SH0;
    A1b = &h0_lds[0][col * SH0 + 32 + kb]; D1 = BT * SH0;
    A2b = &h1_lds[0][col * SH1 + kb];      D2 = BT * SH1;
    Wwr0 = &h1_lds[0][rowq * SH1 + (w - 6) * 16 + col];
    WD = BT * SH1; wstride = SH1;
  } else if (w < 10) {
    // L2: slices 0,1 full.
    lay = 2; threeA = false; doLo = doHi = true;
    const int u = (w - 8) * 16 + col;
    Wz0 = bfragW(k2, 32, 96, u, kb, SZ);
    Wz1 = bfragW(rk2, 32, 96, u, kb, SZ);
    Wr0 = bfragW(k2, 32, 96, 32 + u, kb, SZ);
    Wr1 = bfragW(rk2, 32, 96, 32 + u, kb, SZ);
    Wgx0 = bfragW(k2, 32, 96, 64 + u, kb, SG);
    Wgh1 = bfragW(rk2, 32, 96, 64 + u, kb, SG);
    bz  = SZ * (b2[u] + b2[96 + u]);
    br  = SZ * (b2[32 + u] + b2[96 + 32 + u]);
    bxh = SG * b2[64 + u];
    bhh = SG * b2[96 + 64 + u];
    A0b = &h1_lds[0][col * SH1 + kb]; D0 = BT * SH1;
    A1b = &h2_lds[0][col * SH1 + kb]; D1 = BT * SH1;
    A2b = A1b; D2 = D1;
    Wwr0 = &h2_lds[0][rowq * SH1 + (w - 8) * 16 + col];
    WD = BT * SH1; wstride = SH1;
  } else {
    // L3: slices 0,1 full.
    lay = 3; threeA = false; doLo = doHi = true;
    const int u = (w - 10) * 16 + col;
    Wz0 = bfragW(k3, 32, 96, u, kb, SZ);
    Wz1 = bfragW(rk3, 32, 96, u, kb, SZ);
    Wr0 = bfragW(k3, 32, 96, 32 + u, kb, SZ);
    Wr1 = bfragW(rk3, 32, 96, 32 + u, kb, SZ);
    Wgx0 = bfragW(k3, 32, 96, 64 + u, kb, SG);
    Wgh1 = bfragW(rk3, 32, 96, 64 + u, kb, SG);
    bz  = SZ * (b3[u] + b3[96 + u]);
    br  = SZ * (b3[32 + u] + b3[96 + 32 + u]);
    bxh = SG * b3[64 + u];
    bhh = SG * b3[96 + 64 + u];
    A0b = &h2_lds[0][col * SH1 + kb]; D0 = BT * SH1;
    A1b = &h3_lds[0][col * SH1 + kb]; D1 = BT * SH1;
    A2b = A1b; D2 = D1;
    Wwr0 = &h3_lds[0][rowq * SH1 + (w - 10) * 16 + col];
    WD = BT * SH1; wstride = SH1;
  }

  // bias vectors ride the first MFMA's C operand
  const f32x4 BZ  = {bz, bz, bz, bz};
  const f32x4 BR  = {br, br, br, br};
  const f32x4 BXH = {bxh, bxh, bxh, bxh};
  const f32x4 BHH = {bhh, bhh, bhh, bhh};

  const __bf16* xb = &x_ch[col * 40 + kb];  // L0 x A-frag base (per t-plane)

  // ------------- zero-init h state -------------
  {
    __bf16* p0 = (__bf16*)h0_lds;
    for (int i = tid; i < 2 * BT * SH0; i += NTHR) p0[i] = (__bf16)0.f;
    __bf16* p1 = (__bf16*)h1_lds;
    __bf16* p2 = (__bf16*)h2_lds;
    __bf16* p3 = (__bf16*)h3_lds;
    for (int i = tid; i < 2 * BT * SH1; i += NTHR) {
      p1[i] = (__bf16)0.f; p2[i] = (__bf16)0.f; p3[i] = (__bf16)0.f;
    }
  }
  float hreg[4] = {0.f, 0.f, 0.f, 0.f};
  __syncthreads();

  // Single-division gate: ea/eb/ec are exp2 of the pre-scaled logits.
  //   rg = 1/(1+eb); ec = exp2(gx + rg*gh)
  //   hn = [h*(1+ec) + ea*(1-ec)] / [(1+ea)*(1+ec)]
  // 3 exp2 + 2 rcp + 9 regular VALU per element.
#define GATE(r) { \
    float eb = __builtin_amdgcn_exp2f(ar[r]); \
    float rg = __builtin_amdgcn_rcpf(1.f + eb); \
    float ec = __builtin_amdgcn_exp2f(fmaf(rg, ahh[r], axh[r])); \
    float ea = __builtin_amdgcn_exp2f(az[r]); \
    float rD = __builtin_amdgcn_rcpf((1.f + ea) * (1.f + ec)); \
    float t1 = fmaf(hreg[r], ec, hreg[r]); \
    float t2 = fmaf(ea, -ec, ea); \
    float hn = (t1 + t2) * rD; \
    hreg[r] = hn; \
    wr[(r) * wstride] = (__bf16)hn; }

  for (int s = 0; s < TT + 3; ++s) {
    // ---- bulk x staging every CH steps ----
    if ((s & (CH - 1)) == 0 && s < TT) {
      for (int idx = tid; idx < BT * CH; idx += NTHR) {
        const int row = idx >> 6;          // CH = 64
        const int tg  = idx & (CH - 1);
        const float* p = binp + ((long)row * TT + s + tg) * FF;
        float4 v0 = *(const float4*)(p);
        float4 v1 = *(const float4*)(p + 4);
        float4 v2 = *(const float4*)(p + 8);
        float4 v3 = *(const float4*)(p + 12);
        float4 v4 = *(const float4*)(p + 16);
        float4 e  = *(const float4*)(Wemb + 4 * (int)v0.y);
        __bf16* d = &x_ch[tg * XSTR + row * 40];
        bf16x8 q0 = {(__bf16)v0.x, (__bf16)v0.z, (__bf16)v0.w, (__bf16)v1.x,
                     (__bf16)v1.y, (__bf16)v1.z, (__bf16)v1.w, (__bf16)v2.x};
        bf16x8 q1 = {(__bf16)v2.y, (__bf16)v2.z, (__bf16)v2.w, (__bf16)v3.x,
                     (__bf16)v3.y, (__bf16)v3.z, (__bf16)v3.w, (__bf16)v4.x};
        bf16x8 q2 = {(__bf16)v4.y, (__bf16)v4.z, (__bf16)v4.w, (__bf16)e.x,
                     (__bf16)e.y,  (__bf16)e.z,  (__bf16)e.w,  (__bf16)0.f};
        *(bf16x8*)(d)      = q0;
        *(bf16x8*)(d + 8)  = q1;
        *(bf16x8*)(d + 16) = q2;
        *(bf16x8*)(d + 24) = zf;
      }
      __syncthreads();
    }

    const int pb = (s + 1) & 1;  // read buffer (previous step's writes)
    const int qb = s & 1;        // write buffer
    const int t  = s - lay;

    if (t >= 0 && t < TT) {
      const __bf16* a0p = (lay == 0) ? (xb + (s & (CH - 1)) * XSTR)
                                     : (A0b + pb * D0);
      bf16x8 A0 = *(const bf16x8*)a0p;
      bf16x8 A1 = *(const bf16x8*)(A1b + pb * D1);
      f32x4 az  = mfma16(A0, Wz0, BZ);
      f32x4 ar  = mfma16(A0, Wr0, BR);
      f32x4 axh = mfma16(A0, Wgx0, BXH);
      f32x4 ahh = mfma16(A0, Wgh0, BHH);
      az  = mfma16(A1, Wz1, az);
      ar  = mfma16(A1, Wr1, ar);
      axh = mfma16(A1, Wgx1, axh);
      ahh = mfma16(A1, Wgh1, ahh);
      if (threeA) {
        bf16x8 A2 = *(const bf16x8*)(A2b + pb * D2);
        az  = mfma16(A2, Wz2, az);
        ar  = mfma16(A2, Wr2, ar);
        axh = mfma16(A2, Wgx2, axh);
        ahh = mfma16(A2, Wgh2, ahh);
      }
      __bf16* wr = Wwr0 + qb * WD;

      if (doLo) { GATE(0); GATE(1); }
      if (doHi) { GATE(2); GATE(3); }
    }

    __syncthreads();   // single per-step barrier
  }
#undef GATE

  // ------------- epilogue: logits + softmax -------------
  if (w >= 10) {
#pragma unroll
    for (int r = 0; r < 4; ++r)
      h3f[(rowq + r) * 32 + (w - 10) * 16 + col] = hreg[r];
  }
  __syncthreads();

  if (tid < BT) {
    float l0 = bd[0], l1 = bd[1];
#pragma unroll
    for (int u = 0; u < 32; ++u) {
      float h = h3f[tid * 32 + u];
      l0 = fmaf(h, Wd[2 * u], l0);
      l1 = fmaf(h, Wd[2 * u + 1], l1);
    }
    float m = fmaxf(l0, l1);
    float e0 = __builtin_amdgcn_exp2f((l0 - m) * 1.44269504f);
    float e1 = __builtin_amdgcn_exp2f((l1 - m) * 1.44269504f);
    float inv = 1.f / (e0 + e1);
    out[(bbase + tid) * 2 + 0] = e0 * inv;
    out[(bbase + tid) * 2 + 1] = e1 * inv;
  }
}

extern "C" void kernel_launch(void* const* d_in, const int* in_sizes, int n_in,
                              void* d_out, int out_size, void* d_ws, size_t ws_size,
                              hipStream_t stream) {
  const float* inp  = (const float*)d_in[0];
  const float* Wemb = (const float*)d_in[1];
  const float* k0   = (const float*)d_in[2];
  const float* rk0  = (const float*)d_in[3];
  const float* b0   = (const float*)d_in[4];
  const float* k1   = (const float*)d_in[5];
  const float* rk1  = (const float*)d_in[6];
  const float* b1   = (const float*)d_in[7];
  const float* k2   = (const float*)d_in[8];
  const float* rk2  = (const float*)d_in[9];
  const float* b2   = (const float*)d_in[10];
  const float* k3   = (const float*)d_in[11];
  const float* rk3  = (const float*)d_in[12];
  const float* b3   = (const float*)d_in[13];
  const float* Wd   = (const float*)d_in[14];
  const float* bd   = (const float*)d_in[15];
  float* out = (float*)d_out;

  const int Btot = in_sizes[0] / (TT * FF);   // 4096
  dim3 grid(Btot / BT);                       // 256 blocks
  gru4<<<grid, NTHR, 0, stream>>>(inp, Wemb, k0, rk0, b0, k1, rk1, b1,
                                  k2, rk2, b2, k3, rk3, b3, Wd, bd, out);
}

// Round 7
// 340.450 us; speedup vs baseline: 1.3089x; 1.0062x over previous
//
#include <hip/hip_runtime.h>

// 4-layer GRU stack, B=4096, T=256. 256 persistent blocks x 768 threads
// (12 waves, 3 per SIMD), 16 batch rows per block (one M=16 MFMA tile).
// Proven structure: per-step s_barrier, per-SIMD balanced jobs (every
// SIMD gets {L0-half, full, full} = 50 gate-trans wave-ops/step).
//
// R7 polish (structure unchanged):
//  - chunked main loop (4 x 64 steps + 3-step drain): staging branch and
//    bounds checks out of the hot path; x-plane index = sc (no mask).
//  - #pragma unroll 2: pb/qb/t become alternating compile-time consts.
//  - static s_setprio(1) on full-job waves (halves have slack at every
//    barrier; boost the long-pole waves to shorten the step tail).
//  - weights/biases pre-scaled by -log2e / -2log2e; single-division gate
//    (3 exp2 + 2 rcp per element); biases ride the MFMA C operand.
//    All verified in R6 (absmax 0.00390625).

typedef __attribute__((ext_vector_type(8))) __bf16 bf16x8;
typedef __attribute__((ext_vector_type(4))) float f32x4;

#define TT 256
#define FF 20
#define BT 16
#define CH 64      // x chunk steps held in LDS
#define SH0 72     // h0 LDS row stride (bf16), padded from 64
#define SH1 40     // h1/h2/h3 LDS row stride, padded from 32
#define XSTR 648   // x_ch t-plane stride (bf16): 16*40 + 8 pad
#define NTHR 768

#define SZ (-1.44269504f)   // -log2(e): z/r gate pre-scale
#define SG (-2.88539008f)   // -2*log2(e): candidate-gate pre-scale

__device__ __forceinline__ f32x4 mfma16(bf16x8 a, bf16x8 b, f32x4 c) {
  return __builtin_amdgcn_mfma_f32_16x16x32_bf16(a, b, c, 0, 0, 0);
}

// B-operand fragment from global row-major W[K][N], pre-scaled.
__device__ __forceinline__ bf16x8 bfragW(const float* W, int Kreal, int N,
                                         int ncol, int kbase, float scale) {
  bf16x8 r;
#pragma unroll
  for (int j = 0; j < 8; ++j) {
    int k = kbase + j;
    r[j] = (__bf16)(k < Kreal ? scale * W[k * N + ncol] : 0.f);
  }
  return r;
}

extern "C" __global__ void __launch_bounds__(NTHR, 3)
gru4(const float* __restrict__ inp, const float* __restrict__ Wemb,
     const float* __restrict__ k0, const float* __restrict__ rk0, const float* __restrict__ b0,
     const float* __restrict__ k1, const float* __restrict__ rk1, const float* __restrict__ b1,
     const float* __restrict__ k2, const float* __restrict__ rk2, const float* __restrict__ b2,
     const float* __restrict__ k3, const float* __restrict__ rk3, const float* __restrict__ b3,
     const float* __restrict__ Wd, const float* __restrict__ bd,
     float* __restrict__ out)
{
  __shared__ __align__(16) __bf16 x_ch[CH * XSTR];       // ~83 KB
  __shared__ __align__(16) __bf16 h0_lds[2][BT * SH0];
  __shared__ __align__(16) __bf16 h1_lds[2][BT * SH1];
  __shared__ __align__(16) __bf16 h2_lds[2][BT * SH1];
  __shared__ __align__(16) __bf16 h3_lds[2][BT * SH1];
  __shared__ __align__(16) float h3f[BT * 32];

  const int tid  = threadIdx.x;
  const int lane = tid & 63;
  const int w    = tid >> 6;        // wave 0..11
  const int col  = lane & 15;       // C col / B n / A m index
  const int kb   = (lane >> 4) * 8; // A/B k base within a k-tile
  const int rowq = (lane >> 4) * 4; // C row base (batch)
  const long bbase = (long)blockIdx.x * BT;
  const float* binp = inp + bbase * TT * FF;

  bf16x8 zf;
#pragma unroll
  for (int j = 0; j < 8; ++j) zf[j] = (__bf16)0.f;

  // ---- uniform per-wave job config (shared variables across all roles) ----
  bf16x8 Wz0 = zf, Wz1 = zf, Wz2 = zf;
  bf16x8 Wr0 = zf, Wr1 = zf, Wr2 = zf;
  bf16x8 Wgx0 = zf, Wgx1 = zf, Wgx2 = zf;
  bf16x8 Wgh0 = zf, Wgh1 = zf, Wgh2 = zf;
  float bz = 0.f, br = 0.f, bxh = 0.f, bhh = 0.f;
  const __bf16 *A0b = x_ch, *A1b = x_ch, *A2b = x_ch;
  int D0 = 0, D1 = 0, D2 = 0;
  __bf16* Wwr0 = (__bf16*)h3f;
  int WD = 0, wstride = SH1;
  int lay = 0;
  bool doLo = false, doHi = false, threeA = false;

  if (w < 6) {
    // L0: w0..w3 = row-halves of slices 0,1; w4,w5 = full slices 2,3.
    lay = 0; threeA = true;
    const int sl = (w < 4) ? (w >> 1) : (w - 2);
    doLo = (w >= 4) || ((w & 1) == 0);
    doHi = (w >= 4) || ((w & 1) == 1);
    const int u = sl * 16 + col;
    Wz0 = bfragW(k0, 23, 192, u, kb, SZ);
    Wz1 = bfragW(rk0, 64, 192, u, kb, SZ);
    Wz2 = bfragW(rk0, 64, 192, u, 32 + kb, SZ);
    Wr0 = bfragW(k0, 23, 192, 64 + u, kb, SZ);
    Wr1 = bfragW(rk0, 64, 192, 64 + u, kb, SZ);
    Wr2 = bfragW(rk0, 64, 192, 64 + u, 32 + kb, SZ);
    Wgx0 = bfragW(k0, 23, 192, 128 + u, kb, SG);
    Wgh1 = bfragW(rk0, 64, 192, 128 + u, kb, SG);
    Wgh2 = bfragW(rk0, 64, 192, 128 + u, 32 + kb, SG);
    bz  = SZ * (b0[u] + b0[192 + u]);
    br  = SZ * (b0[64 + u] + b0[192 + 64 + u]);
    bxh = SG * b0[128 + u];
    bhh = SG * b0[192 + 128 + u];
    A1b = &h0_lds[0][col * SH0 + kb];      D1 = BT * SH0;
    A2b = &h0_lds[0][col * SH0 + 32 + kb]; D2 = BT * SH0;
    Wwr0 = &h0_lds[0][rowq * SH0 + sl * 16 + col];
    WD = BT * SH0; wstride = SH0;
  } else if (w < 8) {
    // L1: slices 0,1 full.
    lay = 1; threeA = true; doLo = doHi = true;
    const int u = (w - 6) * 16 + col;
    Wz0 = bfragW(k1, 64, 96, u, kb, SZ);
    Wz1 = bfragW(k1, 64, 96, u, 32 + kb, SZ);
    Wz2 = bfragW(rk1, 32, 96, u, kb, SZ);
    Wr0 = bfragW(k1, 64, 96, 32 + u, kb, SZ);
    Wr1 = bfragW(k1, 64, 96, 32 + u, 32 + kb, SZ);
    Wr2 = bfragW(rk1, 32, 96, 32 + u, kb, SZ);
    Wgx0 = bfragW(k1, 64, 96, 64 + u, kb, SG);
    Wgx1 = bfragW(k1, 64, 96, 64 + u, 32 + kb, SG);
    Wgh2 = bfragW(rk1, 32, 96, 64 + u, kb, SG);
    bz  = SZ * (b1[u] + b1[96 + u]);
    br  = SZ * (b1[32 + u] + b1[96 + 32 + u]);
    bxh = SG * b1[64 + u];
    bhh = SG * b1[96 + 64 + u];
    A0b = &h0_lds[0][col * SH0 + kb];      D0 = BT * SH0;
    A1b = &h0_lds[0][col * SH0 + 32 + kb]; D1 = BT * SH0;
    A2b = &h1_lds[0][col * SH1 + kb];      D2 = BT * SH1;
    Wwr0 = &h1_lds[0][rowq * SH1 + (w - 6) * 16 + col];
    WD = BT * SH1; wstride = SH1;
  } else if (w < 10) {
    // L2: slices 0,1 full.
    lay = 2; threeA = false; doLo = doHi = true;
    const int u = (w - 8) * 16 + col;
    Wz0 = bfragW(k2, 32, 96, u, kb, SZ);
    Wz1 = bfragW(rk2, 32, 96, u, kb, SZ);
    Wr0 = bfragW(k2, 32, 96, 32 + u, kb, SZ);
    Wr1 = bfragW(rk2, 32, 96, 32 + u, kb, SZ);
    Wgx0 = bfragW(k2, 32, 96, 64 + u, kb, SG);
    Wgh1 = bfragW(rk2, 32, 96, 64 + u, kb, SG);
    bz  = SZ * (b2[u] + b2[96 + u]);
    br  = SZ * (b2[32 + u] + b2[96 + 32 + u]);
    bxh = SG * b2[64 + u];
    bhh = SG * b2[96 + 64 + u];
    A0b = &h1_lds[0][col * SH1 + kb]; D0 = BT * SH1;
    A1b = &h2_lds[0][col * SH1 + kb]; D1 = BT * SH1;
    A2b = A1b; D2 = D1;
    Wwr0 = &h2_lds[0][rowq * SH1 + (w - 8) * 16 + col];
    WD = BT * SH1; wstride = SH1;
  } else {
    // L3: slices 0,1 full.
    lay = 3; threeA = false; doLo = doHi = true;
    const int u = (w - 10) * 16 + col;
    Wz0 = bfragW(k3, 32, 96, u, kb, SZ);
    Wz1 = bfragW(rk3, 32, 96, u, kb, SZ);
    Wr0 = bfragW(k3, 32, 96, 32 + u, kb, SZ);
    Wr1 = bfragW(rk3, 32, 96, 32 + u, kb, SZ);
    Wgx0 = bfragW(k3, 32, 96, 64 + u, kb, SG);
    Wgh1 = bfragW(rk3, 32, 96, 64 + u, kb, SG);
    bz  = SZ * (b3[u] + b3[96 + u]);
    br  = SZ * (b3[32 + u] + b3[96 + 32 + u]);
    bxh = SG * b3[64 + u];
    bhh = SG * b3[96 + 64 + u];
    A0b = &h2_lds[0][col * SH1 + kb]; D0 = BT * SH1;
    A1b = &h3_lds[0][col * SH1 + kb]; D1 = BT * SH1;
    A2b = A1b; D2 = D1;
    Wwr0 = &h3_lds[0][rowq * SH1 + (w - 10) * 16 + col];
    WD = BT * SH1; wstride = SH1;
  }

  // bias vectors ride the first MFMA's C operand
  const f32x4 BZ  = {bz, bz, bz, bz};
  const f32x4 BR  = {br, br, br, br};
  const f32x4 BXH = {bxh, bxh, bxh, bxh};
  const f32x4 BHH = {bhh, bhh, bhh, bhh};

  const __bf16* xb = &x_ch[col * 40 + kb];  // L0 x A-frag base (per t-plane)

  // ------------- zero-init h state -------------
  {
    __bf16* p0 = (__bf16*)h0_lds;
    for (int i = tid; i < 2 * BT * SH0; i += NTHR) p0[i] = (__bf16)0.f;
    __bf16* p1 = (__bf16*)h1_lds;
    __bf16* p2 = (__bf16*)h2_lds;
    __bf16* p3 = (__bf16*)h3_lds;
    for (int i = tid; i < 2 * BT * SH1; i += NTHR) {
      p1[i] = (__bf16)0.f; p2[i] = (__bf16)0.f; p3[i] = (__bf16)0.f;
    }
  }
  float hreg[4] = {0.f, 0.f, 0.f, 0.f};

  // Full-job waves are the per-step long pole (2x gate work of halves);
  // statically prioritize them so the barrier tail shortens. Halves have
  // slack at every barrier, so they lose nothing.
  if (doLo && doHi) __builtin_amdgcn_s_setprio(1);

  __syncthreads();

  // Single-division gate: ea/eb/ec are exp2 of the pre-scaled logits.
  //   rg = 1/(1+eb); ec = exp2(gx + rg*gh)
  //   hn = [h*(1+ec) + ea*(1-ec)] / [(1+ea)*(1+ec)]
#define GATE(r) { \
    float eb = __builtin_amdgcn_exp2f(ar[r]); \
    float rg = __builtin_amdgcn_rcpf(1.f + eb); \
    float ec = __builtin_amdgcn_exp2f(fmaf(rg, ahh[r], axh[r])); \
    float ea = __builtin_amdgcn_exp2f(az[r]); \
    float rD = __builtin_amdgcn_rcpf((1.f + ea) * (1.f + ec)); \
    float t1 = fmaf(hreg[r], ec, hreg[r]); \
    float t2 = fmaf(ea, -ec, ea); \
    float hn = (t1 + t2) * rD; \
    hreg[r] = hn; \
    wr[(r) * wstride] = (__bf16)hn; }

#define STEPBODY(S, A0EXPR) { \
    const int pb = ((S) + 1) & 1; \
    const int qb = (S) & 1; \
    const int t  = (S) - lay; \
    if (t >= 0 && t < TT) { \
      bf16x8 A0 = *(const bf16x8*)(A0EXPR); \
      bf16x8 A1 = *(const bf16x8*)(A1b + pb * D1); \
      f32x4 az  = mfma16(A0, Wz0, BZ); \
      f32x4 ar  = mfma16(A0, Wr0, BR); \
      f32x4 axh = mfma16(A0, Wgx0, BXH); \
      f32x4 ahh = mfma16(A0, Wgh0, BHH); \
      az  = mfma16(A1, Wz1, az); \
      ar  = mfma16(A1, Wr1, ar); \
      axh = mfma16(A1, Wgx1, axh); \
      ahh = mfma16(A1, Wgh1, ahh); \
      if (threeA) { \
        bf16x8 A2 = *(const bf16x8*)(A2b + pb * D2); \
        az  = mfma16(A2, Wz2, az); \
        ar  = mfma16(A2, Wr2, ar); \
        axh = mfma16(A2, Wgx2, axh); \
        ahh = mfma16(A2, Wgh2, ahh); \
      } \
      __bf16* wr = Wwr0 + qb * WD; \
      if (doLo) { GATE(0); GATE(1); } \
      if (doHi) { GATE(2); GATE(3); } \
    } \
    __syncthreads(); }

  int s = 0;
  for (int c = 0; c < 4; ++c) {
    // ---- bulk x staging for chunk c (t = c*64 .. c*64+63) ----
    // Previous step's end barrier guarantees chunk c-1 fully consumed.
    for (int idx = tid; idx < BT * CH; idx += NTHR) {
      const int row = idx >> 6;          // CH = 64
      const int tg  = idx & (CH - 1);
      const float* p = binp + ((long)row * TT + c * CH + tg) * FF;
      float4 v0 = *(const float4*)(p);
      float4 v1 = *(const float4*)(p + 4);
      float4 v2 = *(const float4*)(p + 8);
      float4 v3 = *(const float4*)(p + 12);
      float4 v4 = *(const float4*)(p + 16);
      float4 e  = *(const float4*)(Wemb + 4 * (int)v0.y);
      __bf16* d = &x_ch[tg * XSTR + row * 40];
      bf16x8 q0 = {(__bf16)v0.x, (__bf16)v0.z, (__bf16)v0.w, (__bf16)v1.x,
                   (__bf16)v1.y, (__bf16)v1.z, (__bf16)v1.w, (__bf16)v2.x};
      bf16x8 q1 = {(__bf16)v2.y, (__bf16)v2.z, (__bf16)v2.w, (__bf16)v3.x,
                   (__bf16)v3.y, (__bf16)v3.z, (__bf16)v3.w, (__bf16)v4.x};
      bf16x8 q2 = {(__bf16)v4.y, (__bf16)v4.z, (__bf16)v4.w, (__bf16)e.x,
                   (__bf16)e.y,  (__bf16)e.z,  (__bf16)e.w,  (__bf16)0.f};
      *(bf16x8*)(d)      = q0;
      *(bf16x8*)(d + 8)  = q1;
      *(bf16x8*)(d + 16) = q2;
      *(bf16x8*)(d + 24) = zf;
    }
    __syncthreads();

#pragma unroll 2
    for (int sc = 0; sc < CH; ++sc, ++s) {
      STEPBODY(s, (lay == 0) ? (xb + sc * XSTR) : (A0b + ((s + 1) & 1) * D0))
    }
  }

  // ---- drain: 3 skew steps (lay==0 is past TT here, guard excludes it) ----
  for (; s < TT + 3; ++s) {
    STEPBODY(s, A0b + ((s + 1) & 1) * D0)
  }
#undef STEPBODY
#undef GATE

  // ------------- epilogue: logits + softmax -------------
  if (w >= 10) {
#pragma unroll
    for (int r = 0; r < 4; ++r)
      h3f[(rowq + r) * 32 + (w - 10) * 16 + col] = hreg[r];
  }
  __syncthreads();

  if (tid < BT) {
    float l0 = bd[0], l1 = bd[1];
#pragma unroll
    for (int u = 0; u < 32; ++u) {
      float h = h3f[tid * 32 + u];
      l0 = fmaf(h, Wd[2 * u], l0);
      l1 = fmaf(h, Wd[2 * u + 1], l1);
    }
    float m = fmaxf(l0, l1);
    float e0 = __builtin_amdgcn_exp2f((l0 - m) * 1.44269504f);
    float e1 = __builtin_amdgcn_exp2f((l1 - m) * 1.44269504f);
    float inv = 1.f / (e0 + e1);
    out[(bbase + tid) * 2 + 0] = e0 * inv;
    out[(bbase + tid) * 2 + 1] = e1 * inv;
  }
}

extern "C" void kernel_launch(void* const* d_in, const int* in_sizes, int n_in,
                              void* d_out, int out_size, void* d_ws, size_t ws_size,
                              hipStream_t stream) {
  const float* inp  = (const float*)d_in[0];
  const float* Wemb = (const float*)d_in[1];
  const float* k0   = (const float*)d_in[2];
  const float* rk0  = (const float*)d_in[3];
  const float* b0   = (const float*)d_in[4];
  const float* k1   = (const float*)d_in[5];
  const float* rk1  = (const float*)d_in[6];
  const float* b1   = (const float*)d_in[7];
  const float* k2   = (const float*)d_in[8];
  const float* rk2  = (const float*)d_in[9];
  const float* b2   = (const float*)d_in[10];
  const float* k3   = (const float*)d_in[11];
  const float* rk3  = (const float*)d_in[12];
  const float* b3   = (const float*)d_in[13];
  const float* Wd   = (const float*)d_in[14];
  const float* bd   = (const float*)d_in[15];
  float* out = (float*)d_out;

  const int Btot = in_sizes[0] / (TT * FF);   // 4096
  dim3 grid(Btot / BT);                       // 256 blocks
  gru4<<<grid, NTHR, 0, stream>>>(inp, Wemb, k0, rk0, b0, k1, rk1, b1,
                                  k2, rk2, b2, k3, rk3, b3, Wd, bd, out);
}